// Round 8
// baseline (131.513 us; speedup 1.0000x reference)
//
#include <hip/hip_runtime.h>
#include <hip/hip_bf16.h>
#include <math.h>

#define N_ 64
#define S_ 512
#define D_ 768
#define C_ 32
#define KCH 16     // chunks per sequence (scan)
#define LC 32      // steps per chunk (scan)
#define WT_LD 776  // padded K stride for W^T (bf16)
#define BKC 96     // gemm K-chunk (floats)
#define ROWS_PB 128
#define NBLK ((N_ * S_) / ROWS_PB)   // 256

typedef __attribute__((ext_vector_type(8))) short bf16x8;
typedef __attribute__((ext_vector_type(4))) float f32x4;
typedef __attribute__((ext_vector_type(16))) float f32x16;

__device__ inline ushort f2bf(float x) {
    unsigned int b = __builtin_bit_cast(unsigned int, x);
    return (ushort)((b + 0x7FFFu + ((b >> 16) & 1u)) >> 16);   // RNE
}

__device__ inline unsigned cvt_pk_bf16(float lo, float hi) {   // D[15:0]=bf16(lo), D[31:16]=bf16(hi)
    unsigned r;
    asm("v_cvt_pk_bf16_f32 %0, %1, %2" : "=v"(r) : "v"(lo), "v"(hi));
    return r;
}

__device__ __forceinline__ void gload_lds16(const float* g, float* l) {
    __builtin_amdgcn_global_load_lds(
        (const __attribute__((address_space(1))) unsigned int*)g,
        (__attribute__((address_space(3))) unsigned int*)l, 16, 0, 0);
}

// ---------------------------------------------------------------------------
// ONE fused kernel. Block bid covers rows [bid*128, bid*128+128) of npots
// (= sequence n = bid>>2, s-range [sq*128, sq*128+128), sq = bid&3).
// Phase 1: gemm via mfma_f32_16x16x32_bf16. Wave w stages AND computes rows
//          16w..16w+15 -> barrier-free K-loop with counted vmcnt(6) (T4).
// Phase 2: waves 0-3: the block's 4 scan-chunk 32x32 MFMA products from LDS;
//          waves 4-7: the 4 score-window partials from LDS.
// Tail: per-n counter -> LAST of 4 blocks (old==3) combines logZ[n];
//       global counter -> LAST of 64 combiners (old==63) computes the loss.
// Counters are zeroed by a hipMemsetAsync at the top of kernel_launch each
// call, so "old == 3/63" is exactly the last arrival (r7 bug: poisoned start
// residue made the 2nd arrival trigger).
// ---------------------------------------------------------------------------
__global__ __launch_bounds__(512) void crf_fused(const float* __restrict__ X,
                                                 const float* __restrict__ W,
                                                 const float* __restrict__ T,
                                                 const float* __restrict__ labels,
                                                 const float* __restrict__ pad,
                                                 float* __restrict__ npots,
                                                 float* __restrict__ Bg,
                                                 float* __restrict__ chunk_ls,
                                                 float* __restrict__ scores_p,
                                                 float* __restrict__ logZ,
                                                 unsigned* __restrict__ cnt_n,
                                                 unsigned* __restrict__ cnt_all,
                                                 float* __restrict__ out) {
    __shared__ float  Xs[2][ROWS_PB * BKC];   // 2 x 48 KiB
    __shared__ ushort WtS[C_ * WT_LD];        // 48.5 KiB
    __shared__ float  wcomb[32];
    __shared__ int    flagA;

    const int bid = blockIdx.x;
    const int n   = bid >> 2;
    const int sq  = bid & 3;
    const int row0 = bid * ROWS_PB;
    const int tid = threadIdx.x;
    const int w   = tid >> 6;
    const int l   = tid & 63;

    // ---- build W^T bf16 in LDS ----
    for (int i = tid; i < D_ * C_; i += 512) {
        const int k = i >> 5, c = i & 31;
        WtS[c * WT_LD + k] = f2bf(W[i]);
    }
    __syncthreads();

    // ---- phase 1: gemm (barrier-free; wave-self-contained staging) ----
    const int lr = l & 15;
    const int q  = l >> 4;

    // wave w stages granules G in [w*384,(w+1)*384) -> rows 16w..16w+15 only.
    #define STAGE(ck, buf)                                                        \
        {                                                                         \
            _Pragma("unroll")                                                     \
            for (int i_ = 0; i_ < 6; ++i_) {                                      \
                const int G   = (w * 6 + i_) * 64 + l;                            \
                const int row = G / 24;                                           \
                const int g   = G - row * 24;                                     \
                const int gs  = g ^ (row & 7);                                    \
                gload_lds16(X + (size_t)(row0 + row) * D_ + (ck) * BKC + gs * 4,  \
                            &Xs[buf][G * 4]);                                     \
            }                                                                     \
        }

    STAGE(0, 0);
    STAGE(1, 1);

    f32x4 acc0 = {0.f, 0.f, 0.f, 0.f};
    f32x4 acc1 = {0.f, 0.f, 0.f, 0.f};
    const int myrow = w * 16 + lr;
    const int sw    = myrow & 7;
    const ushort* wb0 = &WtS[lr * WT_LD];
    const ushort* wb1 = &WtS[(lr + 16) * WT_LD];

    for (int c = 0; c < D_ / BKC; ++c) {
        if (c < D_ / BKC - 1) asm volatile("s_waitcnt vmcnt(6)" ::: "memory");
        else                  asm volatile("s_waitcnt vmcnt(0)" ::: "memory");
        const float* xb = Xs[c & 1];
        #pragma unroll
        for (int kk = 0; kk < 3; ++kk) {
            const int g0 = 8 * kk + 2 * q;
            const f32x4 alo = *(const f32x4*)&xb[(myrow * 24 + (g0 ^ sw)) * 4];
            const f32x4 ahi = *(const f32x4*)&xb[(myrow * 24 + ((g0 + 1) ^ sw)) * 4];
            union { unsigned u[4]; bf16x8 v; } af;
            af.u[0] = cvt_pk_bf16(alo[0], alo[1]);
            af.u[1] = cvt_pk_bf16(alo[2], alo[3]);
            af.u[2] = cvt_pk_bf16(ahi[0], ahi[1]);
            af.u[3] = cvt_pk_bf16(ahi[2], ahi[3]);
            const int kg = c * BKC + kk * 32 + q * 8;
            const bf16x8 b0 = *(const bf16x8*)(wb0 + kg);
            const bf16x8 b1 = *(const bf16x8*)(wb1 + kg);
            acc0 = __builtin_amdgcn_mfma_f32_16x16x32_bf16(af.v, b0, acc0, 0, 0, 0);
            acc1 = __builtin_amdgcn_mfma_f32_16x16x32_bf16(af.v, b1, acc1, 0, 0, 0);
        }
        if (c < D_ / BKC - 2) {
            asm volatile("s_waitcnt lgkmcnt(0)" ::: "memory");  // buf's ds_reads retired
            STAGE(c + 2, c & 1);
        }
    }
    #undef STAGE

    __syncthreads();   // all Xs reads done before aliasing Xs[0]

    // ---- epilogue: npots -> LDS (np_s) + global ----
    float* np_s = (float*)&Xs[0][0];          // [128][33] (padded, conflict-free)
    float* e_s  = np_s + 128 * 33;            // [4][32*32]
    {
        const int r0l = w * 16 + q * 4;
        #pragma unroll
        for (int reg = 0; reg < 4; ++reg) {
            np_s[(r0l + reg) * 33 + lr]      = acc0[reg];
            np_s[(r0l + reg) * 33 + lr + 16] = acc1[reg];
            npots[(size_t)(row0 + r0l + reg) * C_ + lr]      = acc0[reg];
            npots[(size_t)(row0 + r0l + reg) * C_ + lr + 16] = acc1[reg];
        }
    }
    __syncthreads();

    // ---- phase 2 ----
    int len = 0;
    if (w < 4) {   // chunk-product waves (also compute len; wave 0 reuses it)
        float lsum = 0.f;
        for (int t = l; t < S_; t += 64) lsum += pad[(size_t)n * S_ + t];
        #pragma unroll
        for (int o = 32; o >= 1; o >>= 1) lsum += __shfl_xor(lsum, o);
        len = (int)(lsum + 0.5f);

        const int kg = sq * 4 + w;
        const int lo = kg * LC;
        float* Bout = Bg + ((size_t)n * KCH + kg) * (C_ * C_);
        const int cc = l & 31;
        const int h  = l >> 5;
        const int hi = min(lo + LC, len - 1);

        if (lo >= len - 1) {   // empty chunk -> identity
            #pragma unroll
            for (int qq = 0; qq < 16; ++qq) {
                const int row = (qq & 3) + 8 * (qq >> 2) + 4 * h;
                Bout[row * C_ + cc] = (row == cc) ? 1.f : 0.f;
            }
            if (l == 0) chunk_ls[n * KCH + kg] = 0.f;
        } else {
            const int cnt = hi - lo;
            float* ew = e_s + w * 1024;
            for (int i = l; i < 1024; i += 64) {
                const int rr = i >> 5, c2 = i & 31;
                ew[i] = expf(np_s[(w * 32 + rr) * 33 + c2]);
            }
            asm volatile("s_waitcnt lgkmcnt(0)" ::: "memory");

            float glo[8], ghi[8];
            {
                const float* el = ew + (size_t)(cnt - 1) * C_;
                #pragma unroll
                for (int j = 0; j < 8; ++j) {
                    const int kk = 8 * h + j;
                    glo[j] = el[kk]      * expf(T[kk * C_ + cc]);
                    ghi[j] = el[kk + 16] * expf(T[(kk + 16) * C_ + cc]);
                }
            }

            if (cnt == 1) {
                #pragma unroll
                for (int j = 0; j < 8; ++j) {
                    Bout[(8 * h + j) * C_ + cc]      = glo[j];
                    Bout[(8 * h + j + 16) * C_ + cc] = ghi[j];
                }
                if (l == 0) chunk_ls[n * KCH + kg] = 0.f;
            } else {
                union { unsigned u[4]; bf16x8 v; } ETalo, ETahi, blo, bhi;
                #pragma unroll
                for (int t = 0; t < 4; ++t) {
                    const int kk = 8 * h + 2 * t;
                    ETalo.u[t] = cvt_pk_bf16(expf(T[cc * C_ + kk]),      expf(T[cc * C_ + kk + 1]));
                    ETahi.u[t] = cvt_pk_bf16(expf(T[cc * C_ + kk + 16]), expf(T[cc * C_ + kk + 17]));
                    blo.u[t]   = cvt_pk_bf16(glo[2 * t], glo[2 * t + 1]);
                    bhi.u[t]   = cvt_pk_bf16(ghi[2 * t], ghi[2 * t + 1]);
                }

                float logscale = 0.f;
                int it = 0;
                for (int i = hi - 2; i >= lo; --i) {
                    f32x16 d = {};
                    d = __builtin_amdgcn_mfma_f32_32x32x16_bf16(ETalo.v, blo.v, d, 0, 0, 0);
                    d = __builtin_amdgcn_mfma_f32_32x32x16_bf16(ETahi.v, bhi.v, d, 0, 0, 0);

                    const float* ep = ew + (i - lo) * C_ + 4 * h;
                    const float4 e0 = *(const float4*)(ep);
                    const float4 e1 = *(const float4*)(ep + 8);
                    const float4 e2 = *(const float4*)(ep + 16);
                    const float4 e3 = *(const float4*)(ep + 24);
                    float sd[16];
                    sd[0]  = d[0]  * e0.x;  sd[1]  = d[1]  * e0.y;  sd[2]  = d[2]  * e0.z;  sd[3]  = d[3]  * e0.w;
                    sd[4]  = d[4]  * e1.x;  sd[5]  = d[5]  * e1.y;  sd[6]  = d[6]  * e1.z;  sd[7]  = d[7]  * e1.w;
                    sd[8]  = d[8]  * e2.x;  sd[9]  = d[9]  * e2.y;  sd[10] = d[10] * e2.z;  sd[11] = d[11] * e2.w;
                    sd[12] = d[12] * e3.x;  sd[13] = d[13] * e3.y;  sd[14] = d[14] * e3.z;  sd[15] = d[15] * e3.w;

                    if ((++it & 7) == 0) {
                        float m = sd[0];
                        #pragma unroll
                        for (int qq = 1; qq < 16; ++qq) m = fmaxf(m, sd[qq]);
                        #pragma unroll
                        for (int o = 32; o >= 1; o >>= 1) m = fmaxf(m, __shfl_xor(m, o));
                        logscale += logf(m);
                        const float inv = 1.f / m;
                        #pragma unroll
                        for (int qq = 0; qq < 16; ++qq) sd[qq] *= inv;
                    }

                    if (i > lo) {
                        const unsigned w0 = cvt_pk_bf16(sd[0],  sd[1]);
                        const unsigned w1 = cvt_pk_bf16(sd[2],  sd[3]);
                        const unsigned w2 = cvt_pk_bf16(sd[4],  sd[5]);
                        const unsigned w3 = cvt_pk_bf16(sd[6],  sd[7]);
                        const unsigned w4 = cvt_pk_bf16(sd[8],  sd[9]);
                        const unsigned w5 = cvt_pk_bf16(sd[10], sd[11]);
                        const unsigned w6 = cvt_pk_bf16(sd[12], sd[13]);
                        const unsigned w7 = cvt_pk_bf16(sd[14], sd[15]);
                        const unsigned x0 = (unsigned)__shfl_xor((int)w0, 32);
                        const unsigned x1 = (unsigned)__shfl_xor((int)w1, 32);
                        const unsigned x2 = (unsigned)__shfl_xor((int)w2, 32);
                        const unsigned x3 = (unsigned)__shfl_xor((int)w3, 32);
                        const unsigned x4 = (unsigned)__shfl_xor((int)w4, 32);
                        const unsigned x5 = (unsigned)__shfl_xor((int)w5, 32);
                        const unsigned x6 = (unsigned)__shfl_xor((int)w6, 32);
                        const unsigned x7 = (unsigned)__shfl_xor((int)w7, 32);
                        blo.u[0] = h ? x2 : w0;
                        blo.u[1] = h ? x3 : w1;
                        blo.u[2] = h ? w2 : x0;
                        blo.u[3] = h ? w3 : x1;
                        bhi.u[0] = h ? x6 : w4;
                        bhi.u[1] = h ? x7 : w5;
                        bhi.u[2] = h ? w6 : x4;
                        bhi.u[3] = h ? w7 : x5;
                    } else {
                        #pragma unroll
                        for (int qq = 0; qq < 16; ++qq)
                            Bout[((qq & 3) + 8 * (qq >> 2) + 4 * h) * C_ + cc] = sd[qq];
                    }
                }
                if (l == 0) chunk_ls[n * KCH + kg] = logscale;
            }
        }
    } else {   // score waves
        const int wv = w - 4;
        const int kg = sq * 4 + wv;
        const int tb = kg * LC;
        int best = 0;
        if (l <= LC) {
            const int t = tb - 1 + l;
            if (t >= 0) {
                const float* lrow = labels + ((size_t)n * S_ + t) * C_;
                float bv = lrow[0];
                #pragma unroll
                for (int c = 1; c < C_; ++c) {
                    const float x = lrow[c];
                    if (x > bv) { bv = x; best = c; }
                }
            }
        }
        const int cur = __shfl(best, l + 1);
        float v = 0.f;
        if (l < LC) {
            const int t = tb + l;
            const float p = pad[(size_t)n * S_ + t];
            v = p * np_s[(wv * 32 + l) * 33 + cur];
            if (t >= 1) v = fmaf(p, T[best * C_ + cur], v);
        }
        #pragma unroll
        for (int o = 32; o >= 1; o >>= 1) v += __shfl_xor(v, o);
        if (l == 0) scores_p[n * KCH + kg] = v;
    }

    // ---- tail: per-n combine, then global finalize ----
    __syncthreads();
    __threadfence();
    if (tid == 0) flagA = (atomicAdd(&cnt_n[n], 1u) == 3u) ? 1 : 0;
    __syncthreads();

    if (flagA) {
        __threadfence();   // acquire: other blocks' Bg/chunk_ls/npots/scores
        if (w == 0) {
            const int r  = l & 31;
            const int hh = l >> 5;
            float cls = (l < KCH) ? chunk_ls[n * KCH + l] : 0.f;
            #pragma unroll
            for (int o = 32; o >= 1; o >>= 1) cls += __shfl_xor(cls, o);

            const float np_last = npots[((size_t)n * S_ + (len - 1)) * C_ + r];
            float m0 = np_last;
            #pragma unroll
            for (int o = 32; o >= 1; o >>= 1) m0 = fmaxf(m0, __shfl_xor(m0, o));
            float logscale = m0 + cls;
            if (hh == 0) wcomb[r] = expf(np_last - m0);
            asm volatile("s_waitcnt lgkmcnt(0)" ::: "memory");

            float bv[16];
            {
                const float* Brow = Bg + ((size_t)n * KCH + (KCH - 1)) * (C_ * C_) + r * C_ + hh * 16;
                #pragma unroll
                for (int t = 0; t < 4; ++t) *(float4*)&bv[t * 4] = *(const float4*)(Brow + t * 4);
            }
            float sn = 0.f;
            for (int k2 = KCH - 1; k2 >= 0; --k2) {
                float cb[16];
                #pragma unroll
                for (int t = 0; t < 16; ++t) cb[t] = bv[t];
                if (k2 > 0) {
                    const float* Br2 = Bg + ((size_t)n * KCH + (k2 - 1)) * (C_ * C_) + r * C_ + hh * 16;
                    #pragma unroll
                    for (int t = 0; t < 4; ++t) *(float4*)&bv[t * 4] = *(const float4*)(Br2 + t * 4);
                }
                float wv2[16];
                #pragma unroll
                for (int t = 0; t < 4; ++t) *(float4*)&wv2[t * 4] = *(const float4*)&wcomb[hh * 16 + t * 4];
                float s = 0.f;
                #pragma unroll
                for (int t = 0; t < 16; ++t) s = fmaf(cb[t], wv2[t], s);
                s += __shfl_xor(s, 32);

                float m = s;
                #pragma unroll
                for (int o = 16; o >= 1; o >>= 1) m = fmaxf(m, __shfl_xor(m, o));
                logscale += logf(m);
                sn = s / m;
                if (hh == 0) wcomb[r] = sn;
                asm volatile("s_waitcnt lgkmcnt(0)" ::: "memory");
            }
            float vz = (hh == 0) ? sn : 0.f;
            #pragma unroll
            for (int o = 32; o >= 1; o >>= 1) vz += __shfl_xor(vz, o);
            if (l == 0) logZ[n] = logf(vz) + logscale;
        }
        __threadfence();
        __syncthreads();
        if (tid == 0) flagA = (atomicAdd(cnt_all, 1u) == 63u) ? 1 : 0;
        __syncthreads();
        if (flagA && w == 0) {
            __threadfence();   // acquire: all logZ/scores_p
            float sc = 0.f;
            #pragma unroll
            for (int tb2 = 0; tb2 < KCH; ++tb2) sc += scores_p[l * KCH + tb2];
            float v2 = sc - logZ[l];
            #pragma unroll
            for (int o = 32; o >= 1; o >>= 1) v2 += __shfl_xor(v2, o);
            if (l == 0) out[0] = -v2 / (float)N_;
        }
    }
}

// ---------------------------------------------------------------------------
extern "C" void kernel_launch(void* const* d_in, const int* in_sizes, int n_in,
                              void* d_out, int out_size, void* d_ws, size_t ws_size,
                              hipStream_t stream) {
    const float* X      = (const float*)d_in[0];
    const float* W      = (const float*)d_in[1];
    const float* T      = (const float*)d_in[2];
    const float* labels = (const float*)d_in[3];
    const float* pad    = (const float*)d_in[4];
    float* out = (float*)d_out;

    float*    npots    = (float*)d_ws;                       // 1,048,576 f
    float*    Bg       = npots + (size_t)N_ * S_ * C_;       // 1,048,576 f
    float*    chunk_ls = Bg + (size_t)N_ * KCH * C_ * C_;    // 1024 f
    float*    logZ     = chunk_ls + N_ * KCH;                // 64 f
    float*    scores_p = logZ + N_;                          // 1024 f
    unsigned* cnt_n    = (unsigned*)(scores_p + 1024);       // 64 u32
    unsigned* cnt_all  = cnt_n + N_;                         // 1 u32

    // zero the arrival counters every call (graph-capturable memset node);
    // makes "old == 3 / 63" exactly the LAST arrival, deterministically.
    hipMemsetAsync(cnt_n, 0, (N_ + 1) * sizeof(unsigned), stream);

    crf_fused<<<NBLK, 512, 0, stream>>>(X, W, T, labels, pad, npots, Bg, chunk_ls,
                                        scores_p, logZ, cnt_n, cnt_all, out);
}

// Round 9
// 92.953 us; speedup vs baseline: 1.4148x; 1.4148x over previous
//
#include <hip/hip_runtime.h>
#include <hip/hip_bf16.h>
#include <math.h>

#define N_ 64
#define S_ 512
#define D_ 768
#define C_ 32
#define KCH 16     // chunks per sequence (scan)
#define LC 32      // steps per chunk (scan)
#define WT_LD 776  // padded K stride for W^T (bf16)

typedef __attribute__((ext_vector_type(8))) short bf16x8;
typedef __attribute__((ext_vector_type(4))) float f32x4;
typedef __attribute__((ext_vector_type(16))) float f32x16;

__device__ inline ushort f2bf(float x) {
    unsigned int b = __builtin_bit_cast(unsigned int, x);
    return (ushort)((b + 0x7FFFu + ((b >> 16) & 1u)) >> 16);   // RNE
}

__device__ inline unsigned cvt_pk_bf16(float lo, float hi) {   // D[15:0]=bf16(lo), D[31:16]=bf16(hi)
    unsigned r;
    asm("v_cvt_pk_bf16_f32 %0, %1, %2" : "=v"(r) : "v"(lo), "v"(hi));
    return r;
}

// ---------------------------------------------------------------------------
// K0: Wt[c][k] = bf16(W[k][c])   (r5-verified)
// ---------------------------------------------------------------------------
__global__ __launch_bounds__(256) void wt_prep(const float* __restrict__ W,
                                               ushort* __restrict__ Wt) {
    const int idx = blockIdx.x * 256 + threadIdx.x;
    if (idx < D_ * C_) {
        const int k = idx >> 5, c = idx & 31;
        Wt[c * WT_LD + k] = f2bf(W[idx]);
    }
}

// ---------------------------------------------------------------------------
// K1: npots = X @ W via mfma_f32_16x16x32_bf16. ZERO LDS, zero barriers.
// Wave: 16 rows x 32 cols. Explicit 2-set ping-pong register staging:
// group g = 2 K-chunks (64 floats); while computing set A (8 MFMA-feed loads
// already landed), set B's 8 loads are in flight -> 8KB/wave in flight,
// ~20 waves/CU  =>  HBM-saturated (fixes r5's MLP starvation; avoids r8's
// LDS-aliasing waitcnt collapse).
// ---------------------------------------------------------------------------
__global__ __launch_bounds__(256) void gemm_npots_mfma(const float* __restrict__ X,
                                                       const ushort* __restrict__ Wt,
                                                       float* __restrict__ npots) {
    const int tid  = threadIdx.x;
    const int wv   = tid >> 6;
    const int l    = tid & 63;
    const int lr   = l & 15;
    const int q    = l >> 4;
    const int m0   = blockIdx.x * 64 + wv * 16;

    const float*  xrow = X + (size_t)(m0 + lr) * D_ + q * 8;
    const ushort* wb0  = Wt + lr * WT_LD + q * 8;
    const ushort* wb1  = wb0 + 16 * WT_LD;

    f32x4  Aalo[2], Aahi[2], Balo[2], Bahi[2];
    bf16x8 Ab0[2],  Ab1[2],  Bb0[2],  Bb1[2];
    f32x4 acc0 = {0.f, 0.f, 0.f, 0.f};
    f32x4 acc1 = {0.f, 0.f, 0.f, 0.f};

    // group g covers chunks 2g, 2g+1 (chunk = 32 floats of K); 12 groups.
    #define LOADG(S, g)                                                      \
        {                                                                    \
            _Pragma("unroll")                                                \
            for (int j = 0; j < 2; ++j) {                                    \
                const int c_ = (g) * 2 + j;                                  \
                S##alo[j] = *(const f32x4*)(xrow + c_ * 32);                 \
                S##ahi[j] = *(const f32x4*)(xrow + c_ * 32 + 4);             \
                S##b0[j]  = *(const bf16x8*)(wb0 + c_ * 32);                 \
                S##b1[j]  = *(const bf16x8*)(wb1 + c_ * 32);                 \
            }                                                                \
        }

    #define COMPG(S)                                                         \
        {                                                                    \
            _Pragma("unroll")                                                \
            for (int j = 0; j < 2; ++j) {                                    \
                union { unsigned u[4]; bf16x8 v; } af;                       \
                af.u[0] = cvt_pk_bf16(S##alo[j][0], S##alo[j][1]);           \
                af.u[1] = cvt_pk_bf16(S##alo[j][2], S##alo[j][3]);           \
                af.u[2] = cvt_pk_bf16(S##ahi[j][0], S##ahi[j][1]);           \
                af.u[3] = cvt_pk_bf16(S##ahi[j][2], S##ahi[j][3]);           \
                acc0 = __builtin_amdgcn_mfma_f32_16x16x32_bf16(af.v, S##b0[j], acc0, 0, 0, 0); \
                acc1 = __builtin_amdgcn_mfma_f32_16x16x32_bf16(af.v, S##b1[j], acc1, 0, 0, 0); \
            }                                                                \
        }

    LOADG(A, 0);
    LOADG(B, 1);
    for (int g = 0; g < 6; ++g) {
        COMPG(A);
        if (g < 5) LOADG(A, 2 * g + 2);
        COMPG(B);
        if (g < 5) LOADG(B, 2 * g + 3);
    }
    #undef LOADG
    #undef COMPG

    const int r0 = m0 + q * 4;   // D: col=lane&15, row=(lane>>4)*4+reg
    #pragma unroll
    for (int reg = 0; reg < 4; ++reg) {
        npots[(size_t)(r0 + reg) * C_ + lr]      = acc0[reg];
        npots[(size_t)(r0 + reg) * C_ + lr + 16] = acc1[reg];
    }
}

// ---------------------------------------------------------------------------
// K2: block (n,k), 128 thr. Wave0: chunk 32x32 MFMA product (r6-verified math,
// returns converted to if/else). Wave1: score partial (r6-verified).
// Tail (r8-verified machinery): per-n counter -> last of 16 blocks combines
// logZ[n]; global counter -> last of 64 combiners computes the loss.
// Counters zeroed by hipMemsetAsync each call.
// ---------------------------------------------------------------------------
__global__ __launch_bounds__(128) void chunk_score_tail(const float* __restrict__ npots,
                                                        const float* __restrict__ pad,
                                                        const float* __restrict__ T,
                                                        const float* __restrict__ labels,
                                                        float* __restrict__ Bg,
                                                        float* __restrict__ chunk_ls,
                                                        float* __restrict__ scores_p,
                                                        float* __restrict__ logZ,
                                                        unsigned* __restrict__ cnt_n,
                                                        unsigned* __restrict__ cnt_all,
                                                        float* __restrict__ out) {
    const int n = blockIdx.x, k = blockIdx.y;
    const int tid = threadIdx.x;
    const int l = tid & 63;
    __shared__ __align__(16) float e_lds[LC * C_];
    __shared__ __align__(16) float wcomb[32];
    __shared__ int flagA;

    int len = 0;
    if (tid < 64) {
        // ---------------- wave 0: chunk matrix product ----------------
        const int cc = l & 31;
        const int h  = l >> 5;

        const float* pm = pad + (size_t)n * S_;
        float lsum = 0.f;
        for (int t = l; t < S_; t += 64) lsum += pm[t];
        #pragma unroll
        for (int o = 32; o >= 1; o >>= 1) lsum += __shfl_xor(lsum, o);
        len = (int)(lsum + 0.5f);

        float* Bout = Bg + ((size_t)n * KCH + k) * (C_ * C_);
        const int lo = k * LC;
        const int hi = min(lo + LC, len - 1);

        if (lo >= len - 1) {   // empty chunk -> identity
            #pragma unroll
            for (int qq = 0; qq < 16; ++qq) {
                const int row = (qq & 3) + 8 * (qq >> 2) + 4 * h;
                Bout[row * C_ + cc] = (row == cc) ? 1.f : 0.f;
            }
            if (l == 0) chunk_ls[n * KCH + k] = 0.f;
        } else {
            const int cnt = hi - lo;
            const float* npn = npots + ((size_t)n * S_ + lo) * C_;
            for (int qd = l * 4; qd < cnt * C_; qd += 256) {
                const float4 v = *(const float4*)(npn + qd);
                *(float4*)&e_lds[qd] = make_float4(expf(v.x), expf(v.y), expf(v.z), expf(v.w));
            }
            asm volatile("s_waitcnt lgkmcnt(0)" ::: "memory");

            float glo[8], ghi[8];
            {
                const float* el = e_lds + (size_t)(cnt - 1) * C_;
                #pragma unroll
                for (int j = 0; j < 8; ++j) {
                    const int kk = 8 * h + j;
                    glo[j] = el[kk]      * expf(T[kk * C_ + cc]);
                    ghi[j] = el[kk + 16] * expf(T[(kk + 16) * C_ + cc]);
                }
            }

            if (cnt == 1) {
                #pragma unroll
                for (int j = 0; j < 8; ++j) {
                    Bout[(8 * h + j) * C_ + cc]      = glo[j];
                    Bout[(8 * h + j + 16) * C_ + cc] = ghi[j];
                }
                if (l == 0) chunk_ls[n * KCH + k] = 0.f;
            } else {
                union { unsigned u[4]; bf16x8 v; } ETalo, ETahi, blo, bhi;
                #pragma unroll
                for (int t = 0; t < 4; ++t) {
                    const int kk = 8 * h + 2 * t;
                    ETalo.u[t] = cvt_pk_bf16(expf(T[cc * C_ + kk]),      expf(T[cc * C_ + kk + 1]));
                    ETahi.u[t] = cvt_pk_bf16(expf(T[cc * C_ + kk + 16]), expf(T[cc * C_ + kk + 17]));
                    blo.u[t]   = cvt_pk_bf16(glo[2 * t], glo[2 * t + 1]);
                    bhi.u[t]   = cvt_pk_bf16(ghi[2 * t], ghi[2 * t + 1]);
                }

                float logscale = 0.f;
                int it = 0;
                for (int i = hi - 2; i >= lo; --i) {
                    f32x16 d = {};
                    d = __builtin_amdgcn_mfma_f32_32x32x16_bf16(ETalo.v, blo.v, d, 0, 0, 0);
                    d = __builtin_amdgcn_mfma_f32_32x32x16_bf16(ETahi.v, bhi.v, d, 0, 0, 0);

                    const float* ep = e_lds + (i - lo) * C_ + 4 * h;
                    const float4 e0 = *(const float4*)(ep);
                    const float4 e1 = *(const float4*)(ep + 8);
                    const float4 e2 = *(const float4*)(ep + 16);
                    const float4 e3 = *(const float4*)(ep + 24);
                    float sd[16];
                    sd[0]  = d[0]  * e0.x;  sd[1]  = d[1]  * e0.y;  sd[2]  = d[2]  * e0.z;  sd[3]  = d[3]  * e0.w;
                    sd[4]  = d[4]  * e1.x;  sd[5]  = d[5]  * e1.y;  sd[6]  = d[6]  * e1.z;  sd[7]  = d[7]  * e1.w;
                    sd[8]  = d[8]  * e2.x;  sd[9]  = d[9]  * e2.y;  sd[10] = d[10] * e2.z;  sd[11] = d[11] * e2.w;
                    sd[12] = d[12] * e3.x;  sd[13] = d[13] * e3.y;  sd[14] = d[14] * e3.z;  sd[15] = d[15] * e3.w;

                    if ((++it & 7) == 0) {
                        float m = sd[0];
                        #pragma unroll
                        for (int qq = 1; qq < 16; ++qq) m = fmaxf(m, sd[qq]);
                        #pragma unroll
                        for (int o = 32; o >= 1; o >>= 1) m = fmaxf(m, __shfl_xor(m, o));
                        logscale += logf(m);
                        const float inv = 1.f / m;
                        #pragma unroll
                        for (int qq = 0; qq < 16; ++qq) sd[qq] *= inv;
                    }

                    if (i > lo) {
                        const unsigned w0 = cvt_pk_bf16(sd[0],  sd[1]);
                        const unsigned w1 = cvt_pk_bf16(sd[2],  sd[3]);
                        const unsigned w2 = cvt_pk_bf16(sd[4],  sd[5]);
                        const unsigned w3 = cvt_pk_bf16(sd[6],  sd[7]);
                        const unsigned w4 = cvt_pk_bf16(sd[8],  sd[9]);
                        const unsigned w5 = cvt_pk_bf16(sd[10], sd[11]);
                        const unsigned w6 = cvt_pk_bf16(sd[12], sd[13]);
                        const unsigned w7 = cvt_pk_bf16(sd[14], sd[15]);
                        const unsigned x0 = (unsigned)__shfl_xor((int)w0, 32);
                        const unsigned x1 = (unsigned)__shfl_xor((int)w1, 32);
                        const unsigned x2 = (unsigned)__shfl_xor((int)w2, 32);
                        const unsigned x3 = (unsigned)__shfl_xor((int)w3, 32);
                        const unsigned x4 = (unsigned)__shfl_xor((int)w4, 32);
                        const unsigned x5 = (unsigned)__shfl_xor((int)w5, 32);
                        const unsigned x6 = (unsigned)__shfl_xor((int)w6, 32);
                        const unsigned x7 = (unsigned)__shfl_xor((int)w7, 32);
                        blo.u[0] = h ? x2 : w0;
                        blo.u[1] = h ? x3 : w1;
                        blo.u[2] = h ? w2 : x0;
                        blo.u[3] = h ? w3 : x1;
                        bhi.u[0] = h ? x6 : w4;
                        bhi.u[1] = h ? x7 : w5;
                        bhi.u[2] = h ? w6 : x4;
                        bhi.u[3] = h ? w7 : x5;
                    } else {
                        #pragma unroll
                        for (int qq = 0; qq < 16; ++qq)
                            Bout[((qq & 3) + 8 * (qq >> 2) + 4 * h) * C_ + cc] = sd[qq];
                    }
                }
                if (l == 0) chunk_ls[n * KCH + k] = logscale;
            }
        }
    } else {
        // ---------------- wave 1: score partial ----------------
        const int tb = k * LC;
        int best = 0;
        if (l <= LC) {
            const int t = tb - 1 + l;
            if (t >= 0) {
                const float* lrow = labels + ((size_t)n * S_ + t) * C_;
                float bv = lrow[0];
                #pragma unroll
                for (int c = 1; c < C_; ++c) {
                    const float x = lrow[c];
                    if (x > bv) { bv = x; best = c; }
                }
            }
        }
        const int cur = __shfl(best, l + 1);
        float v = 0.f;
        if (l < LC) {
            const int t = tb + l;
            const float p = pad[(size_t)n * S_ + t];
            v = p * npots[((size_t)n * S_ + t) * C_ + cur];
            if (t >= 1) v = fmaf(p, T[best * C_ + cur], v);
        }
        #pragma unroll
        for (int o = 32; o >= 1; o >>= 1) v += __shfl_xor(v, o);
        if (l == 0) scores_p[n * KCH + k] = v;
    }

    // ---- tail: per-n combine, then global finalize (r8-verified) ----
    __syncthreads();
    __threadfence();
    if (tid == 0) flagA = (atomicAdd(&cnt_n[n], 1u) == (KCH - 1)) ? 1 : 0;
    __syncthreads();

    if (flagA) {
        __threadfence();   // acquire: other blocks' Bg/chunk_ls/scores
        if (tid < 64) {
            const int r  = l & 31;
            const int hh = l >> 5;
            float cls = (l < KCH) ? chunk_ls[n * KCH + l] : 0.f;
            #pragma unroll
            for (int o = 32; o >= 1; o >>= 1) cls += __shfl_xor(cls, o);

            const float np_last = npots[((size_t)n * S_ + (len - 1)) * C_ + r];
            float m0 = np_last;
            #pragma unroll
            for (int o = 32; o >= 1; o >>= 1) m0 = fmaxf(m0, __shfl_xor(m0, o));
            float logscale = m0 + cls;
            if (hh == 0) wcomb[r] = expf(np_last - m0);
            asm volatile("s_waitcnt lgkmcnt(0)" ::: "memory");

            float bv[16];
            {
                const float* Brow = Bg + ((size_t)n * KCH + (KCH - 1)) * (C_ * C_) + r * C_ + hh * 16;
                #pragma unroll
                for (int t = 0; t < 4; ++t) *(float4*)&bv[t * 4] = *(const float4*)(Brow + t * 4);
            }
            float sn = 0.f;
            for (int k2 = KCH - 1; k2 >= 0; --k2) {
                float cb[16];
                #pragma unroll
                for (int t = 0; t < 16; ++t) cb[t] = bv[t];
                if (k2 > 0) {
                    const float* Br2 = Bg + ((size_t)n * KCH + (k2 - 1)) * (C_ * C_) + r * C_ + hh * 16;
                    #pragma unroll
                    for (int t = 0; t < 4; ++t) *(float4*)&bv[t * 4] = *(const float4*)(Br2 + t * 4);
                }
                float wv2[16];
                #pragma unroll
                for (int t = 0; t < 4; ++t) *(float4*)&wv2[t * 4] = *(const float4*)&wcomb[hh * 16 + t * 4];
                float s = 0.f;
                #pragma unroll
                for (int t = 0; t < 16; ++t) s = fmaf(cb[t], wv2[t], s);
                s += __shfl_xor(s, 32);

                float m = s;
                #pragma unroll
                for (int o = 16; o >= 1; o >>= 1) m = fmaxf(m, __shfl_xor(m, o));
                logscale += logf(m);
                sn = s / m;
                if (hh == 0) wcomb[r] = sn;
                asm volatile("s_waitcnt lgkmcnt(0)" ::: "memory");
            }
            float vz = (hh == 0) ? sn : 0.f;
            #pragma unroll
            for (int o = 32; o >= 1; o >>= 1) vz += __shfl_xor(vz, o);
            if (l == 0) logZ[n] = logf(vz) + logscale;
        }
        __threadfence();
        __syncthreads();
        if (tid == 0) flagA = (atomicAdd(cnt_all, 1u) == (N_ - 1)) ? 1 : 0;
        __syncthreads();
        if (flagA && tid < 64) {
            __threadfence();   // acquire: all logZ/scores_p
            float sc = 0.f;
            #pragma unroll
            for (int tb2 = 0; tb2 < KCH; ++tb2) sc += scores_p[l * KCH + tb2];
            float v2 = sc - logZ[l];
            #pragma unroll
            for (int o = 32; o >= 1; o >>= 1) v2 += __shfl_xor(v2, o);
            if (l == 0) out[0] = -v2 / (float)N_;
        }
    }
}

// ---------------------------------------------------------------------------
extern "C" void kernel_launch(void* const* d_in, const int* in_sizes, int n_in,
                              void* d_out, int out_size, void* d_ws, size_t ws_size,
                              hipStream_t stream) {
    const float* X      = (const float*)d_in[0];
    const float* W      = (const float*)d_in[1];
    const float* T      = (const float*)d_in[2];
    const float* labels = (const float*)d_in[3];
    const float* pad    = (const float*)d_in[4];
    float* out = (float*)d_out;

    float*    npots    = (float*)d_ws;                       // 1,048,576 f
    float*    Bg       = npots + (size_t)N_ * S_ * C_;       // 1,048,576 f
    float*    chunk_ls = Bg + (size_t)N_ * KCH * C_ * C_;    // 1024 f
    float*    logZ     = chunk_ls + N_ * KCH;                // 64 f
    float*    scores_p = logZ + N_;                          // 1024 f
    unsigned* cnt_n    = (unsigned*)(scores_p + 1024);       // 64 u32
    unsigned* cnt_all  = cnt_n + N_;                         // 1 u32
    ushort*   Wt       = (ushort*)(cnt_n + 68);              // 32*776 bf16 (16B-aligned)

    // zero the arrival counters every call (graph-capturable memset node)
    hipMemsetAsync(cnt_n, 0, (N_ + 1) * sizeof(unsigned), stream);

    wt_prep<<<96, 256, 0, stream>>>(W, Wt);
    gemm_npots_mfma<<<(N_ * S_) / 64, 256, 0, stream>>>(X, Wt, npots);
    chunk_score_tail<<<dim3(N_, KCH), 128, 0, stream>>>(npots, pad, T, labels, Bg,
                                                        chunk_ls, scores_p, logZ,
                                                        cnt_n, cnt_all, out);
}

// Round 10
// 61.928 us; speedup vs baseline: 2.1236x; 1.5010x over previous
//
#include <hip/hip_runtime.h>
#include <hip/hip_bf16.h>
#include <math.h>

#define N_ 64
#define S_ 512
#define D_ 768
#define C_ 32
#define KCH 16     // chunks per sequence (scan)
#define LC 32      // steps per chunk (scan)
#define WT_LD 776  // padded K stride for W^T (bf16)
#define BS_LD 36   // padded row stride of B in LDS (b128-aligned, low-conflict)
#define BS_PER (C_ * BS_LD)

typedef __attribute__((ext_vector_type(8))) short bf16x8;
typedef __attribute__((ext_vector_type(4))) float f32x4;
typedef __attribute__((ext_vector_type(16))) float f32x16;

__device__ inline ushort f2bf(float x) {
    unsigned int b = __builtin_bit_cast(unsigned int, x);
    return (ushort)((b + 0x7FFFu + ((b >> 16) & 1u)) >> 16);   // RNE
}

__device__ inline unsigned cvt_pk_bf16(float lo, float hi) {   // D[15:0]=bf16(lo), D[31:16]=bf16(hi)
    unsigned r;
    asm("v_cvt_pk_bf16_f32 %0, %1, %2" : "=v"(r) : "v"(lo), "v"(hi));
    return r;
}

// ---------------------------------------------------------------------------
// K0: Wt[c][k] = bf16(W[k][c])   (r5-verified)
// ---------------------------------------------------------------------------
__global__ __launch_bounds__(256) void wt_prep(const float* __restrict__ W,
                                               ushort* __restrict__ Wt) {
    const int idx = blockIdx.x * 256 + threadIdx.x;
    if (idx < D_ * C_) {
        const int k = idx >> 5, c = idx & 31;
        Wt[c * WT_LD + k] = f2bf(W[idx]);
    }
}

// ---------------------------------------------------------------------------
// K1: npots = X @ W via mfma_f32_16x16x32_bf16. ZERO LDS, zero barriers.
// 2-set ping-pong register staging (r9-verified, ~15-20 us).
// ---------------------------------------------------------------------------
__global__ __launch_bounds__(256) void gemm_npots_mfma(const float* __restrict__ X,
                                                       const ushort* __restrict__ Wt,
                                                       float* __restrict__ npots) {
    const int tid  = threadIdx.x;
    const int wv   = tid >> 6;
    const int l    = tid & 63;
    const int lr   = l & 15;
    const int q    = l >> 4;
    const int m0   = blockIdx.x * 64 + wv * 16;

    const float*  xrow = X + (size_t)(m0 + lr) * D_ + q * 8;
    const ushort* wb0  = Wt + lr * WT_LD + q * 8;
    const ushort* wb1  = wb0 + 16 * WT_LD;

    f32x4  Aalo[2], Aahi[2], Balo[2], Bahi[2];
    bf16x8 Ab0[2],  Ab1[2],  Bb0[2],  Bb1[2];
    f32x4 acc0 = {0.f, 0.f, 0.f, 0.f};
    f32x4 acc1 = {0.f, 0.f, 0.f, 0.f};

    #define LOADG(S, g)                                                      \
        {                                                                    \
            _Pragma("unroll")                                                \
            for (int j = 0; j < 2; ++j) {                                    \
                const int c_ = (g) * 2 + j;                                  \
                S##alo[j] = *(const f32x4*)(xrow + c_ * 32);                 \
                S##ahi[j] = *(const f32x4*)(xrow + c_ * 32 + 4);             \
                S##b0[j]  = *(const bf16x8*)(wb0 + c_ * 32);                 \
                S##b1[j]  = *(const bf16x8*)(wb1 + c_ * 32);                 \
            }                                                                \
        }

    #define COMPG(S)                                                         \
        {                                                                    \
            _Pragma("unroll")                                                \
            for (int j = 0; j < 2; ++j) {                                    \
                union { unsigned u[4]; bf16x8 v; } af;                       \
                af.u[0] = cvt_pk_bf16(S##alo[j][0], S##alo[j][1]);           \
                af.u[1] = cvt_pk_bf16(S##alo[j][2], S##alo[j][3]);           \
                af.u[2] = cvt_pk_bf16(S##ahi[j][0], S##ahi[j][1]);           \
                af.u[3] = cvt_pk_bf16(S##ahi[j][2], S##ahi[j][3]);           \
                acc0 = __builtin_amdgcn_mfma_f32_16x16x32_bf16(af.v, S##b0[j], acc0, 0, 0, 0); \
                acc1 = __builtin_amdgcn_mfma_f32_16x16x32_bf16(af.v, S##b1[j], acc1, 0, 0, 0); \
            }                                                                \
        }

    LOADG(A, 0);
    LOADG(B, 1);
    for (int g = 0; g < 6; ++g) {
        COMPG(A);
        if (g < 5) LOADG(A, 2 * g + 2);
        COMPG(B);
        if (g < 5) LOADG(B, 2 * g + 3);
    }
    #undef LOADG
    #undef COMPG

    const int r0 = m0 + q * 4;
    #pragma unroll
    for (int reg = 0; reg < 4; ++reg) {
        npots[(size_t)(r0 + reg) * C_ + lr]      = acc0[reg];
        npots[(size_t)(r0 + reg) * C_ + lr + 16] = acc1[reg];
    }
}

// ---------------------------------------------------------------------------
// K2: crf_scan — one block per sequence n, 1024 thr (16 waves).
// Wave w: chunk-w 32x32 MFMA product (B -> LDS Bs[w], pad-36) + score window w.
// Then __syncthreads(); wave 0 combines the 16 B's from LDS -> logZ_n, sums
// scores, and atomically accumulates (score_n - logZ_n) into accum. The 64th
// arrival reads the total and writes out. NO __threadfence anywhere (r9: 1024
// device-scope fences cost ~60 us).
// ---------------------------------------------------------------------------
__global__ __launch_bounds__(1024) void crf_scan(const float* __restrict__ npots,
                                                 const float* __restrict__ pad,
                                                 const float* __restrict__ T,
                                                 const float* __restrict__ labels,
                                                 float* __restrict__ accum,
                                                 unsigned* __restrict__ cnt_all,
                                                 float* __restrict__ out) {
    __shared__ float e_s[KCH * LC * C_];   // 64 KiB (wave-private slabs)
    __shared__ float Bs[KCH * BS_PER];     // 72 KiB
    __shared__ float cls_s[KCH];
    __shared__ float sc_s[KCH];
    __shared__ __align__(16) float wcomb[32];

    const int n   = blockIdx.x;
    const int tid = threadIdx.x;
    const int w   = tid >> 6;    // wave = chunk k
    const int l   = tid & 63;
    const int cc  = l & 31;
    const int h   = l >> 5;

    // ---- per-wave: sequence length ----
    const float* pm = pad + (size_t)n * S_;
    float lsum = 0.f;
    for (int t = l; t < S_; t += 64) lsum += pm[t];
    #pragma unroll
    for (int o = 32; o >= 1; o >>= 1) lsum += __shfl_xor(lsum, o);
    const int len = (int)(lsum + 0.5f);

    // ---- per-wave: chunk product into Bs[w] ----
    {
        const int k  = w;
        const int lo = k * LC;
        const int hi = min(lo + LC, len - 1);
        float* Bout = &Bs[w * BS_PER];

        if (lo >= len - 1) {   // empty chunk -> identity
            #pragma unroll
            for (int qq = 0; qq < 16; ++qq) {
                const int row = (qq & 3) + 8 * (qq >> 2) + 4 * h;
                Bout[row * BS_LD + cc] = (row == cc) ? 1.f : 0.f;
            }
            if (l == 0) cls_s[w] = 0.f;
        } else {
            const int cnt = hi - lo;
            float* ew = &e_s[w * (LC * C_)];
            const float* npn = npots + ((size_t)n * S_ + lo) * C_;
            for (int qd = l * 4; qd < cnt * C_; qd += 256) {
                const float4 v = *(const float4*)(npn + qd);
                *(float4*)&ew[qd] = make_float4(expf(v.x), expf(v.y), expf(v.z), expf(v.w));
            }
            asm volatile("s_waitcnt lgkmcnt(0)" ::: "memory");   // wave-local LDS visibility

            float glo[8], ghi[8];
            {
                const float* el = ew + (size_t)(cnt - 1) * C_;
                #pragma unroll
                for (int j = 0; j < 8; ++j) {
                    const int kk = 8 * h + j;
                    glo[j] = el[kk]      * expf(T[kk * C_ + cc]);
                    ghi[j] = el[kk + 16] * expf(T[(kk + 16) * C_ + cc]);
                }
            }

            if (cnt == 1) {
                #pragma unroll
                for (int j = 0; j < 8; ++j) {
                    Bout[(8 * h + j) * BS_LD + cc]        = glo[j];
                    Bout[(8 * h + j + 16) * BS_LD + cc]   = ghi[j];
                }
                if (l == 0) cls_s[w] = 0.f;
            } else {
                union { unsigned u[4]; bf16x8 v; } ETalo, ETahi, blo, bhi;
                #pragma unroll
                for (int t = 0; t < 4; ++t) {
                    const int kk = 8 * h + 2 * t;
                    ETalo.u[t] = cvt_pk_bf16(expf(T[cc * C_ + kk]),      expf(T[cc * C_ + kk + 1]));
                    ETahi.u[t] = cvt_pk_bf16(expf(T[cc * C_ + kk + 16]), expf(T[cc * C_ + kk + 17]));
                    blo.u[t]   = cvt_pk_bf16(glo[2 * t], glo[2 * t + 1]);
                    bhi.u[t]   = cvt_pk_bf16(ghi[2 * t], ghi[2 * t + 1]);
                }

                float logscale = 0.f;
                int it = 0;
                for (int i = hi - 2; i >= lo; --i) {
                    f32x16 d = {};
                    d = __builtin_amdgcn_mfma_f32_32x32x16_bf16(ETalo.v, blo.v, d, 0, 0, 0);
                    d = __builtin_amdgcn_mfma_f32_32x32x16_bf16(ETahi.v, bhi.v, d, 0, 0, 0);

                    const float* ep = ew + (i - lo) * C_ + 4 * h;
                    const float4 e0 = *(const float4*)(ep);
                    const float4 e1 = *(const float4*)(ep + 8);
                    const float4 e2 = *(const float4*)(ep + 16);
                    const float4 e3 = *(const float4*)(ep + 24);
                    float sd[16];
                    sd[0]  = d[0]  * e0.x;  sd[1]  = d[1]  * e0.y;  sd[2]  = d[2]  * e0.z;  sd[3]  = d[3]  * e0.w;
                    sd[4]  = d[4]  * e1.x;  sd[5]  = d[5]  * e1.y;  sd[6]  = d[6]  * e1.z;  sd[7]  = d[7]  * e1.w;
                    sd[8]  = d[8]  * e2.x;  sd[9]  = d[9]  * e2.y;  sd[10] = d[10] * e2.z;  sd[11] = d[11] * e2.w;
                    sd[12] = d[12] * e3.x;  sd[13] = d[13] * e3.y;  sd[14] = d[14] * e3.z;  sd[15] = d[15] * e3.w;

                    if ((++it & 7) == 0) {
                        float m = sd[0];
                        #pragma unroll
                        for (int qq = 1; qq < 16; ++qq) m = fmaxf(m, sd[qq]);
                        #pragma unroll
                        for (int o = 32; o >= 1; o >>= 1) m = fmaxf(m, __shfl_xor(m, o));
                        logscale += logf(m);
                        const float inv = 1.f / m;
                        #pragma unroll
                        for (int qq = 0; qq < 16; ++qq) sd[qq] *= inv;
                    }

                    if (i > lo) {
                        const unsigned w0 = cvt_pk_bf16(sd[0],  sd[1]);
                        const unsigned w1 = cvt_pk_bf16(sd[2],  sd[3]);
                        const unsigned w2 = cvt_pk_bf16(sd[4],  sd[5]);
                        const unsigned w3 = cvt_pk_bf16(sd[6],  sd[7]);
                        const unsigned w4 = cvt_pk_bf16(sd[8],  sd[9]);
                        const unsigned w5 = cvt_pk_bf16(sd[10], sd[11]);
                        const unsigned w6 = cvt_pk_bf16(sd[12], sd[13]);
                        const unsigned w7 = cvt_pk_bf16(sd[14], sd[15]);
                        const unsigned x0 = (unsigned)__shfl_xor((int)w0, 32);
                        const unsigned x1 = (unsigned)__shfl_xor((int)w1, 32);
                        const unsigned x2 = (unsigned)__shfl_xor((int)w2, 32);
                        const unsigned x3 = (unsigned)__shfl_xor((int)w3, 32);
                        const unsigned x4 = (unsigned)__shfl_xor((int)w4, 32);
                        const unsigned x5 = (unsigned)__shfl_xor((int)w5, 32);
                        const unsigned x6 = (unsigned)__shfl_xor((int)w6, 32);
                        const unsigned x7 = (unsigned)__shfl_xor((int)w7, 32);
                        blo.u[0] = h ? x2 : w0;
                        blo.u[1] = h ? x3 : w1;
                        blo.u[2] = h ? w2 : x0;
                        blo.u[3] = h ? w3 : x1;
                        bhi.u[0] = h ? x6 : w4;
                        bhi.u[1] = h ? x7 : w5;
                        bhi.u[2] = h ? w6 : x4;
                        bhi.u[3] = h ? w7 : x5;
                    } else {
                        #pragma unroll
                        for (int qq = 0; qq < 16; ++qq)
                            Bout[((qq & 3) + 8 * (qq >> 2) + 4 * h) * BS_LD + cc] = sd[qq];
                    }
                }
                if (l == 0) cls_s[w] = logscale;
            }
        }
    }

    // ---- per-wave: score partial for window w ----
    {
        const int tb = w * LC;
        int best = 0;
        if (l <= LC) {
            const int t = tb - 1 + l;
            if (t >= 0) {
                const float* lrow = labels + ((size_t)n * S_ + t) * C_;
                float bv = lrow[0];
                #pragma unroll
                for (int c = 1; c < C_; ++c) {
                    const float x = lrow[c];
                    if (x > bv) { bv = x; best = c; }
                }
            }
        }
        const int cur = __shfl(best, l + 1);
        float v = 0.f;
        if (l < LC) {
            const int t = tb + l;
            const float p = pad[(size_t)n * S_ + t];
            v = p * npots[((size_t)n * S_ + t) * C_ + cur];
            if (t >= 1) v = fmaf(p, T[best * C_ + cur], v);
        }
        #pragma unroll
        for (int o = 32; o >= 1; o >>= 1) v += __shfl_xor(v, o);
        if (l == 0) sc_s[w] = v;
    }

    __syncthreads();

    // ---- wave 0: combine from LDS, accumulate loss ----
    if (w == 0) {
        const int r  = l & 31;
        const int hh = l >> 5;

        float cls = (l < KCH) ? cls_s[l] : 0.f;
        #pragma unroll
        for (int o = 32; o >= 1; o >>= 1) cls += __shfl_xor(cls, o);

        float sc = (l < KCH) ? sc_s[l] : 0.f;
        #pragma unroll
        for (int o = 32; o >= 1; o >>= 1) sc += __shfl_xor(sc, o);

        const float np_last = npots[((size_t)n * S_ + (len - 1)) * C_ + r];
        float m0 = np_last;
        #pragma unroll
        for (int o = 32; o >= 1; o >>= 1) m0 = fmaxf(m0, __shfl_xor(m0, o));
        float logscale = m0 + cls;
        if (hh == 0) wcomb[r] = expf(np_last - m0);
        asm volatile("s_waitcnt lgkmcnt(0)" ::: "memory");

        float sn = 0.f;
        for (int k2 = KCH - 1; k2 >= 0; --k2) {
            float cb[16], wv2[16];
            const float* Brow = &Bs[k2 * BS_PER + r * BS_LD + hh * 16];
            #pragma unroll
            for (int t = 0; t < 4; ++t) *(float4*)&cb[t * 4] = *(const float4*)(Brow + t * 4);
            #pragma unroll
            for (int t = 0; t < 4; ++t) *(float4*)&wv2[t * 4] = *(const float4*)&wcomb[hh * 16 + t * 4];
            float s = 0.f;
            #pragma unroll
            for (int t = 0; t < 16; ++t) s = fmaf(cb[t], wv2[t], s);
            s += __shfl_xor(s, 32);

            float m = s;
            #pragma unroll
            for (int o = 16; o >= 1; o >>= 1) m = fmaxf(m, __shfl_xor(m, o));
            logscale += logf(m);
            sn = s / m;
            if (hh == 0) wcomb[r] = sn;
            asm volatile("s_waitcnt lgkmcnt(0)" ::: "memory");
        }
        float vz = (hh == 0) ? sn : 0.f;
        #pragma unroll
        for (int o = 32; o >= 1; o >>= 1) vz += __shfl_xor(vz, o);
        const float logZn = logf(vz) + logscale;

        if (l == 0) {
            atomicAdd(accum, sc - logZn);                       // device-scope RMW
            asm volatile("s_waitcnt vmcnt(0)" ::: "memory");    // add performed
            const unsigned old = atomicAdd(cnt_all, 1u);
            if (old == (unsigned)(N_ - 1)) {
                const float total = atomicAdd(accum, 0.f);      // atomic read of final sum
                out[0] = -total / (float)N_;
            }
        }
    }
}

// ---------------------------------------------------------------------------
extern "C" void kernel_launch(void* const* d_in, const int* in_sizes, int n_in,
                              void* d_out, int out_size, void* d_ws, size_t ws_size,
                              hipStream_t stream) {
    const float* X      = (const float*)d_in[0];
    const float* W      = (const float*)d_in[1];
    const float* T      = (const float*)d_in[2];
    const float* labels = (const float*)d_in[3];
    const float* pad    = (const float*)d_in[4];
    float* out = (float*)d_out;

    float*    npots   = (float*)d_ws;                    // 1,048,576 f
    float*    accum   = npots + (size_t)N_ * S_ * C_;    // 1 f
    unsigned* cnt_all = (unsigned*)(accum + 1);          // 1 u32
    ushort*   Wt      = (ushort*)(accum + 4);            // 32*776 bf16 (16B-aligned)

    // zero loss accumulator + arrival counter each call (graph-capturable)
    hipMemsetAsync(accum, 0, 8, stream);

    wt_prep<<<96, 256, 0, stream>>>(W, Wt);
    gemm_npots_mfma<<<(N_ * S_) / 64, 256, 0, stream>>>(X, Wt, npots);
    crf_scan<<<N_, 1024, 0, stream>>>(npots, pad, T, labels, accum, cnt_all, out);
}

// Round 11
// 55.592 us; speedup vs baseline: 2.3657x; 1.1140x over previous
//
#include <hip/hip_runtime.h>
#include <hip/hip_bf16.h>
#include <math.h>

#define N_ 64
#define S_ 512
#define D_ 768
#define C_ 32
#define KCH 16     // chunks per sequence (scan)
#define LC 32      // steps per chunk (scan)
#define WT_LD 772  // padded K stride for W^T in LDS (stride 1544 B == 8 mod 128)
#define BS_LD 36   // padded row stride of B in LDS
#define BS_PER (C_ * BS_LD)

typedef __attribute__((ext_vector_type(8))) short bf16x8;
typedef __attribute__((ext_vector_type(4))) float f32x4;
typedef __attribute__((ext_vector_type(16))) float f32x16;

__device__ inline ushort f2bf(float x) {
    unsigned int b = __builtin_bit_cast(unsigned int, x);
    return (ushort)((b + 0x7FFFu + ((b >> 16) & 1u)) >> 16);   // RNE
}

__device__ inline unsigned cvt_pk_bf16(float lo, float hi) {   // D[15:0]=bf16(lo), D[31:16]=bf16(hi)
    unsigned r;
    asm("v_cvt_pk_bf16_f32 %0, %1, %2" : "=v"(r) : "v"(lo), "v"(hi));
    return r;
}

// ---------------------------------------------------------------------------
// K1: npots = X @ W via mfma_f32_16x16x32_bf16.
// 256 blocks x 512 thr (8 waves), 128 rows/block. W^T built as bf16 in LDS
// once per block (r6-verified pattern); K-loop is barrier-free: X via 2-deep
// register ping-pong (r9/r10-verified), B-fragments via ds_read_b128 from the
// read-only WtS. Block 0 also zero-inits accum/cnt_all for K2 (kernel-boundary
// ordering) — removes the memset and wt_prep graph nodes.
// ---------------------------------------------------------------------------
__global__ __launch_bounds__(512) void gemm_npots_mfma(const float* __restrict__ X,
                                                       const float* __restrict__ W,
                                                       float* __restrict__ npots,
                                                       float* __restrict__ accum,
                                                       unsigned* __restrict__ cnt_all) {
    __shared__ ushort WtS[C_ * WT_LD];   // 49.4 KiB
    const int tid = threadIdx.x;

    if (blockIdx.x == 0 && tid == 0) { accum[0] = 0.f; cnt_all[0] = 0u; }

    // build W^T bf16 in LDS (coalesced W reads)
    for (int i = tid; i < D_ * C_; i += 512) {
        const int k = i >> 5, c = i & 31;
        WtS[c * WT_LD + k] = f2bf(W[i]);
    }
    __syncthreads();

    const int w  = tid >> 6;
    const int l  = tid & 63;
    const int lr = l & 15;
    const int q  = l >> 4;
    const int m0 = blockIdx.x * 128 + w * 16;

    const float*  xrow = X + (size_t)(m0 + lr) * D_ + q * 8;
    const ushort* wb0  = &WtS[lr * WT_LD + q * 8];
    const ushort* wb1  = wb0 + 16 * WT_LD;

    f32x4  Aalo[2], Aahi[2], Balo[2], Bahi[2];
    f32x4 acc0 = {0.f, 0.f, 0.f, 0.f};
    f32x4 acc1 = {0.f, 0.f, 0.f, 0.f};

    // group g covers chunks 2g, 2g+1 (chunk = 32 floats of K); 12 groups.
    #define LOADG(S, g)                                                      \
        {                                                                    \
            _Pragma("unroll")                                                \
            for (int j = 0; j < 2; ++j) {                                    \
                const int c_ = (g) * 2 + j;                                  \
                S##alo[j] = *(const f32x4*)(xrow + c_ * 32);                 \
                S##ahi[j] = *(const f32x4*)(xrow + c_ * 32 + 4);             \
            }                                                                \
        }

    #define COMPG(S, g)                                                      \
        {                                                                    \
            _Pragma("unroll")                                                \
            for (int j = 0; j < 2; ++j) {                                    \
                const int c_ = (g) * 2 + j;                                  \
                union { unsigned u[4]; bf16x8 v; } af;                       \
                af.u[0] = cvt_pk_bf16(S##alo[j][0], S##alo[j][1]);           \
                af.u[1] = cvt_pk_bf16(S##alo[j][2], S##alo[j][3]);           \
                af.u[2] = cvt_pk_bf16(S##ahi[j][0], S##ahi[j][1]);           \
                af.u[3] = cvt_pk_bf16(S##ahi[j][2], S##ahi[j][3]);           \
                const bf16x8 b0 = *(const bf16x8*)(wb0 + c_ * 32);           \
                const bf16x8 b1 = *(const bf16x8*)(wb1 + c_ * 32);           \
                acc0 = __builtin_amdgcn_mfma_f32_16x16x32_bf16(af.v, b0, acc0, 0, 0, 0); \
                acc1 = __builtin_amdgcn_mfma_f32_16x16x32_bf16(af.v, b1, acc1, 0, 0, 0); \
            }                                                                \
        }

    LOADG(A, 0);
    LOADG(B, 1);
    for (int g = 0; g < 6; ++g) {
        COMPG(A, 2 * g);
        if (g < 5) LOADG(A, 2 * g + 2);
        COMPG(B, 2 * g + 1);
        if (g < 5) LOADG(B, 2 * g + 3);
    }
    #undef LOADG
    #undef COMPG

    const int r0 = m0 + q * 4;   // D: col=lane&15, row=(lane>>4)*4+reg
    #pragma unroll
    for (int reg = 0; reg < 4; ++reg) {
        npots[(size_t)(r0 + reg) * C_ + lr]      = acc0[reg];
        npots[(size_t)(r0 + reg) * C_ + lr + 16] = acc1[reg];
    }
}

// ---------------------------------------------------------------------------
// K2: crf_scan — one block per sequence n, 1024 thr (16 waves). (r10-verified)
// Wave w: chunk-w 32x32 MFMA product (B -> LDS Bs[w]) + score window w.
// __syncthreads(); wave 0 combines from LDS -> logZ_n, accumulates loss via
// device atomics; 64th arrival writes out. No threadfence (r9 lesson).
// ---------------------------------------------------------------------------
__global__ __launch_bounds__(1024) void crf_scan(const float* __restrict__ npots,
                                                 const float* __restrict__ pad,
                                                 const float* __restrict__ T,
                                                 const float* __restrict__ labels,
                                                 float* __restrict__ accum,
                                                 unsigned* __restrict__ cnt_all,
                                                 float* __restrict__ out) {
    __shared__ float e_s[KCH * LC * C_];   // 64 KiB (wave-private slabs)
    __shared__ float Bs[KCH * BS_PER];     // 72 KiB
    __shared__ float cls_s[KCH];
    __shared__ float sc_s[KCH];
    __shared__ __align__(16) float wcomb[32];

    const int n   = blockIdx.x;
    const int tid = threadIdx.x;
    const int w   = tid >> 6;    // wave = chunk k
    const int l   = tid & 63;
    const int cc  = l & 31;
    const int h   = l >> 5;

    // ---- per-wave: sequence length ----
    const float* pm = pad + (size_t)n * S_;
    float lsum = 0.f;
    for (int t = l; t < S_; t += 64) lsum += pm[t];
    #pragma unroll
    for (int o = 32; o >= 1; o >>= 1) lsum += __shfl_xor(lsum, o);
    const int len = (int)(lsum + 0.5f);

    // ---- per-wave: chunk product into Bs[w] ----
    {
        const int k  = w;
        const int lo = k * LC;
        const int hi = min(lo + LC, len - 1);
        float* Bout = &Bs[w * BS_PER];

        if (lo >= len - 1) {   // empty chunk -> identity
            #pragma unroll
            for (int qq = 0; qq < 16; ++qq) {
                const int row = (qq & 3) + 8 * (qq >> 2) + 4 * h;
                Bout[row * BS_LD + cc] = (row == cc) ? 1.f : 0.f;
            }
            if (l == 0) cls_s[w] = 0.f;
        } else {
            const int cnt = hi - lo;
            float* ew = &e_s[w * (LC * C_)];
            const float* npn = npots + ((size_t)n * S_ + lo) * C_;
            for (int qd = l * 4; qd < cnt * C_; qd += 256) {
                const float4 v = *(const float4*)(npn + qd);
                *(float4*)&ew[qd] = make_float4(expf(v.x), expf(v.y), expf(v.z), expf(v.w));
            }
            asm volatile("s_waitcnt lgkmcnt(0)" ::: "memory");   // wave-local LDS visibility

            float glo[8], ghi[8];
            {
                const float* el = ew + (size_t)(cnt - 1) * C_;
                #pragma unroll
                for (int j = 0; j < 8; ++j) {
                    const int kk = 8 * h + j;
                    glo[j] = el[kk]      * expf(T[kk * C_ + cc]);
                    ghi[j] = el[kk + 16] * expf(T[(kk + 16) * C_ + cc]);
                }
            }

            if (cnt == 1) {
                #pragma unroll
                for (int j = 0; j < 8; ++j) {
                    Bout[(8 * h + j) * BS_LD + cc]      = glo[j];
                    Bout[(8 * h + j + 16) * BS_LD + cc] = ghi[j];
                }
                if (l == 0) cls_s[w] = 0.f;
            } else {
                union { unsigned u[4]; bf16x8 v; } ETalo, ETahi, blo, bhi;
                #pragma unroll
                for (int t = 0; t < 4; ++t) {
                    const int kk = 8 * h + 2 * t;
                    ETalo.u[t] = cvt_pk_bf16(expf(T[cc * C_ + kk]),      expf(T[cc * C_ + kk + 1]));
                    ETahi.u[t] = cvt_pk_bf16(expf(T[cc * C_ + kk + 16]), expf(T[cc * C_ + kk + 17]));
                    blo.u[t]   = cvt_pk_bf16(glo[2 * t], glo[2 * t + 1]);
                    bhi.u[t]   = cvt_pk_bf16(ghi[2 * t], ghi[2 * t + 1]);
                }

                float logscale = 0.f;
                int it = 0;
                for (int i = hi - 2; i >= lo; --i) {
                    f32x16 d = {};
                    d = __builtin_amdgcn_mfma_f32_32x32x16_bf16(ETalo.v, blo.v, d, 0, 0, 0);
                    d = __builtin_amdgcn_mfma_f32_32x32x16_bf16(ETahi.v, bhi.v, d, 0, 0, 0);

                    const float* ep = ew + (i - lo) * C_ + 4 * h;
                    const float4 e0 = *(const float4*)(ep);
                    const float4 e1 = *(const float4*)(ep + 8);
                    const float4 e2 = *(const float4*)(ep + 16);
                    const float4 e3 = *(const float4*)(ep + 24);
                    float sd[16];
                    sd[0]  = d[0]  * e0.x;  sd[1]  = d[1]  * e0.y;  sd[2]  = d[2]  * e0.z;  sd[3]  = d[3]  * e0.w;
                    sd[4]  = d[4]  * e1.x;  sd[5]  = d[5]  * e1.y;  sd[6]  = d[6]  * e1.z;  sd[7]  = d[7]  * e1.w;
                    sd[8]  = d[8]  * e2.x;  sd[9]  = d[9]  * e2.y;  sd[10] = d[10] * e2.z;  sd[11] = d[11] * e2.w;
                    sd[12] = d[12] * e3.x;  sd[13] = d[13] * e3.y;  sd[14] = d[14] * e3.z;  sd[15] = d[15] * e3.w;

                    if ((++it & 7) == 0) {
                        float m = sd[0];
                        #pragma unroll
                        for (int qq = 1; qq < 16; ++qq) m = fmaxf(m, sd[qq]);
                        #pragma unroll
                        for (int o = 32; o >= 1; o >>= 1) m = fmaxf(m, __shfl_xor(m, o));
                        logscale += logf(m);
                        const float inv = 1.f / m;
                        #pragma unroll
                        for (int qq = 0; qq < 16; ++qq) sd[qq] *= inv;
                    }

                    if (i > lo) {
                        const unsigned w0 = cvt_pk_bf16(sd[0],  sd[1]);
                        const unsigned w1 = cvt_pk_bf16(sd[2],  sd[3]);
                        const unsigned w2 = cvt_pk_bf16(sd[4],  sd[5]);
                        const unsigned w3 = cvt_pk_bf16(sd[6],  sd[7]);
                        const unsigned w4 = cvt_pk_bf16(sd[8],  sd[9]);
                        const unsigned w5 = cvt_pk_bf16(sd[10], sd[11]);
                        const unsigned w6 = cvt_pk_bf16(sd[12], sd[13]);
                        const unsigned w7 = cvt_pk_bf16(sd[14], sd[15]);
                        const unsigned x0 = (unsigned)__shfl_xor((int)w0, 32);
                        const unsigned x1 = (unsigned)__shfl_xor((int)w1, 32);
                        const unsigned x2 = (unsigned)__shfl_xor((int)w2, 32);
                        const unsigned x3 = (unsigned)__shfl_xor((int)w3, 32);
                        const unsigned x4 = (unsigned)__shfl_xor((int)w4, 32);
                        const unsigned x5 = (unsigned)__shfl_xor((int)w5, 32);
                        const unsigned x6 = (unsigned)__shfl_xor((int)w6, 32);
                        const unsigned x7 = (unsigned)__shfl_xor((int)w7, 32);
                        blo.u[0] = h ? x2 : w0;
                        blo.u[1] = h ? x3 : w1;
                        blo.u[2] = h ? w2 : x0;
                        blo.u[3] = h ? w3 : x1;
                        bhi.u[0] = h ? x6 : w4;
                        bhi.u[1] = h ? x7 : w5;
                        bhi.u[2] = h ? w6 : x4;
                        bhi.u[3] = h ? w7 : x5;
                    } else {
                        #pragma unroll
                        for (int qq = 0; qq < 16; ++qq)
                            Bout[((qq & 3) + 8 * (qq >> 2) + 4 * h) * BS_LD + cc] = sd[qq];
                    }
                }
                if (l == 0) cls_s[w] = logscale;
            }
        }
    }

    // ---- per-wave: score partial for window w ----
    {
        const int tb = w * LC;
        int best = 0;
        if (l <= LC) {
            const int t = tb - 1 + l;
            if (t >= 0) {
                const float* lrow = labels + ((size_t)n * S_ + t) * C_;
                float bv = lrow[0];
                #pragma unroll
                for (int c = 1; c < C_; ++c) {
                    const float x = lrow[c];
                    if (x > bv) { bv = x; best = c; }
                }
            }
        }
        const int cur = __shfl(best, l + 1);
        float v = 0.f;
        if (l < LC) {
            const int t = tb + l;
            const float p = pad[(size_t)n * S_ + t];
            v = p * npots[((size_t)n * S_ + t) * C_ + cur];
            if (t >= 1) v = fmaf(p, T[best * C_ + cur], v);
        }
        #pragma unroll
        for (int o = 32; o >= 1; o >>= 1) v += __shfl_xor(v, o);
        if (l == 0) sc_s[w] = v;
    }

    __syncthreads();

    // ---- wave 0: combine from LDS, accumulate loss ----
    if (w == 0) {
        const int r  = l & 31;
        const int hh = l >> 5;

        float cls = (l < KCH) ? cls_s[l] : 0.f;
        #pragma unroll
        for (int o = 32; o >= 1; o >>= 1) cls += __shfl_xor(cls, o);

        float sc = (l < KCH) ? sc_s[l] : 0.f;
        #pragma unroll
        for (int o = 32; o >= 1; o >>= 1) sc += __shfl_xor(sc, o);

        const float np_last = npots[((size_t)n * S_ + (len - 1)) * C_ + r];
        float m0 = np_last;
        #pragma unroll
        for (int o = 32; o >= 1; o >>= 1) m0 = fmaxf(m0, __shfl_xor(m0, o));
        float logscale = m0 + cls;
        if (hh == 0) wcomb[r] = expf(np_last - m0);
        asm volatile("s_waitcnt lgkmcnt(0)" ::: "memory");

        float sn = 0.f;
        for (int k2 = KCH - 1; k2 >= 0; --k2) {
            float cb[16], wv2[16];
            const float* Brow = &Bs[k2 * BS_PER + r * BS_LD + hh * 16];
            #pragma unroll
            for (int t = 0; t < 4; ++t) *(float4*)&cb[t * 4] = *(const float4*)(Brow + t * 4);
            #pragma unroll
            for (int t = 0; t < 4; ++t) *(float4*)&wv2[t * 4] = *(const float4*)&wcomb[hh * 16 + t * 4];
            float s = 0.f;
            #pragma unroll
            for (int t = 0; t < 16; ++t) s = fmaf(cb[t], wv2[t], s);
            s += __shfl_xor(s, 32);

            float m = s;
            #pragma unroll
            for (int o = 16; o >= 1; o >>= 1) m = fmaxf(m, __shfl_xor(m, o));
            logscale += logf(m);
            sn = s / m;
            if (hh == 0) wcomb[r] = sn;
            asm volatile("s_waitcnt lgkmcnt(0)" ::: "memory");
        }
        float vz = (hh == 0) ? sn : 0.f;
        #pragma unroll
        for (int o = 32; o >= 1; o >>= 1) vz += __shfl_xor(vz, o);
        const float logZn = logf(vz) + logscale;

        if (l == 0) {
            atomicAdd(accum, sc - logZn);                       // device-scope RMW
            asm volatile("s_waitcnt vmcnt(0)" ::: "memory");    // add performed
            const unsigned old = atomicAdd(cnt_all, 1u);
            if (old == (unsigned)(N_ - 1)) {
                const float total = atomicAdd(accum, 0.f);      // atomic read of final sum
                out[0] = -total / (float)N_;
            }
        }
    }
}

// ---------------------------------------------------------------------------
extern "C" void kernel_launch(void* const* d_in, const int* in_sizes, int n_in,
                              void* d_out, int out_size, void* d_ws, size_t ws_size,
                              hipStream_t stream) {
    const float* X      = (const float*)d_in[0];
    const float* W      = (const float*)d_in[1];
    const float* T      = (const float*)d_in[2];
    const float* labels = (const float*)d_in[3];
    const float* pad    = (const float*)d_in[4];
    float* out = (float*)d_out;

    float*    npots   = (float*)d_ws;                    // 1,048,576 f
    float*    accum   = npots + (size_t)N_ * S_ * C_;    // 1 f
    unsigned* cnt_all = (unsigned*)(accum + 1);          // 1 u32

    gemm_npots_mfma<<<(N_ * S_) / 128, 512, 0, stream>>>(X, W, npots, accum, cnt_all);
    crf_scan<<<N_, 1024, 0, stream>>>(npots, pad, T, labels, accum, cnt_all, out);
}

// Round 12
// 54.737 us; speedup vs baseline: 2.4026x; 1.0156x over previous
//
#include <hip/hip_runtime.h>
#include <hip/hip_bf16.h>
#include <math.h>

#define N_ 64
#define S_ 512
#define D_ 768
#define C_ 32
#define KCH 16     // chunks per sequence (scan)
#define LC 32      // steps per chunk (scan)
#define WT_LD 772  // padded K stride for W^T in LDS

typedef __attribute__((ext_vector_type(8))) short bf16x8;
typedef __attribute__((ext_vector_type(4))) float f32x4;
typedef __attribute__((ext_vector_type(16))) float f32x16;

__device__ inline ushort f2bf(float x) {
    unsigned int b = __builtin_bit_cast(unsigned int, x);
    return (ushort)((b + 0x7FFFu + ((b >> 16) & 1u)) >> 16);   // RNE
}

__device__ inline unsigned cvt_pk_bf16(float lo, float hi) {   // D[15:0]=bf16(lo), D[31:16]=bf16(hi)
    unsigned r;
    asm("v_cvt_pk_bf16_f32 %0, %1, %2" : "=v"(r) : "v"(lo), "v"(hi));
    return r;
}

// ---------------------------------------------------------------------------
// K1: npots = X @ W via mfma_f32_16x16x32_bf16.  (r11-verified, UNCHANGED)
// 256 blocks x 512 thr, 128 rows/block, W^T bf16 in LDS, barrier-free K-loop
// with 2-deep register ping-pong. Block 0 zero-inits accum/cnt_all.
// ---------------------------------------------------------------------------
__global__ __launch_bounds__(512) void gemm_npots_mfma(const float* __restrict__ X,
                                                       const float* __restrict__ W,
                                                       float* __restrict__ npots,
                                                       float* __restrict__ accum,
                                                       unsigned* __restrict__ cnt_all) {
    __shared__ ushort WtS[C_ * WT_LD];   // 49.4 KiB
    const int tid = threadIdx.x;

    if (blockIdx.x == 0 && tid == 0) { accum[0] = 0.f; cnt_all[0] = 0u; }

    for (int i = tid; i < D_ * C_; i += 512) {
        const int k = i >> 5, c = i & 31;
        WtS[c * WT_LD + k] = f2bf(W[i]);
    }
    __syncthreads();

    const int w  = tid >> 6;
    const int l  = tid & 63;
    const int lr = l & 15;
    const int q  = l >> 4;
    const int m0 = blockIdx.x * 128 + w * 16;

    const float*  xrow = X + (size_t)(m0 + lr) * D_ + q * 8;
    const ushort* wb0  = &WtS[lr * WT_LD + q * 8];
    const ushort* wb1  = wb0 + 16 * WT_LD;

    f32x4  Aalo[2], Aahi[2], Balo[2], Bahi[2];
    f32x4 acc0 = {0.f, 0.f, 0.f, 0.f};
    f32x4 acc1 = {0.f, 0.f, 0.f, 0.f};

    #define LOADG(S, g)                                                      \
        {                                                                    \
            _Pragma("unroll")                                                \
            for (int j = 0; j < 2; ++j) {                                    \
                const int c_ = (g) * 2 + j;                                  \
                S##alo[j] = *(const f32x4*)(xrow + c_ * 32);                 \
                S##ahi[j] = *(const f32x4*)(xrow + c_ * 32 + 4);             \
            }                                                                \
        }

    #define COMPG(S, g)                                                      \
        {                                                                    \
            _Pragma("unroll")                                                \
            for (int j = 0; j < 2; ++j) {                                    \
                const int c_ = (g) * 2 + j;                                  \
                union { unsigned u[4]; bf16x8 v; } af;                       \
                af.u[0] = cvt_pk_bf16(S##alo[j][0], S##alo[j][1]);           \
                af.u[1] = cvt_pk_bf16(S##alo[j][2], S##alo[j][3]);           \
                af.u[2] = cvt_pk_bf16(S##ahi[j][0], S##ahi[j][1]);           \
                af.u[3] = cvt_pk_bf16(S##ahi[j][2], S##ahi[j][3]);           \
                const bf16x8 b0 = *(const bf16x8*)(wb0 + c_ * 32);           \
                const bf16x8 b1 = *(const bf16x8*)(wb1 + c_ * 32);           \
                acc0 = __builtin_amdgcn_mfma_f32_16x16x32_bf16(af.v, b0, acc0, 0, 0, 0); \
                acc1 = __builtin_amdgcn_mfma_f32_16x16x32_bf16(af.v, b1, acc1, 0, 0, 0); \
            }                                                                \
        }

    LOADG(A, 0);
    LOADG(B, 1);
    for (int g = 0; g < 6; ++g) {
        COMPG(A, 2 * g);
        if (g < 5) LOADG(A, 2 * g + 2);
        COMPG(B, 2 * g + 1);
        if (g < 5) LOADG(B, 2 * g + 3);
    }
    #undef LOADG
    #undef COMPG

    const int r0 = m0 + q * 4;
    #pragma unroll
    for (int reg = 0; reg < 4; ++reg) {
        npots[(size_t)(r0 + reg) * C_ + lr]      = acc0[reg];
        npots[(size_t)(r0 + reg) * C_ + lr + 16] = acc1[reg];
    }
}

// ---------------------------------------------------------------------------
// K2: block (n,k), 128 thr, 1024 blocks spread over all CUs (4 blocks/CU —
// the r6-verified structure; r10/r11's fused 16-wave version was LDS-pipe
// bound on 64 CUs). Wave0: chunk product -> global Bg. Wave1: score partial.
// Shfl exchange halved: 4 pre-selected __shfl_xor instead of 8.
// ---------------------------------------------------------------------------
__global__ __launch_bounds__(128) void chunk_score(const float* __restrict__ npots,
                                                   const float* __restrict__ pad,
                                                   const float* __restrict__ T,
                                                   const float* __restrict__ labels,
                                                   float* __restrict__ Bg,
                                                   float* __restrict__ chunk_ls,
                                                   float* __restrict__ scores_p) {
    const int n = blockIdx.x, k = blockIdx.y;
    const int tid = threadIdx.x;
    const int l = tid & 63;
    __shared__ __align__(16) float e_lds[LC * C_];

    if (tid >= 64) {
        // ---------------- wave 1: score partial (r6-verified) ----------
        const int tb = k * LC;
        int best = 0;
        if (l <= LC) {
            const int t = tb - 1 + l;
            if (t >= 0) {
                const float* lrow = labels + ((size_t)n * S_ + t) * C_;
                float bv = lrow[0];
                #pragma unroll
                for (int c = 1; c < C_; ++c) {
                    const float x = lrow[c];
                    if (x > bv) { bv = x; best = c; }
                }
            }
        }
        const int cur = __shfl(best, l + 1);
        float v = 0.f;
        if (l < LC) {
            const int t = tb + l;
            const float p = pad[(size_t)n * S_ + t];
            v = p * npots[((size_t)n * S_ + t) * C_ + cur];
            if (t >= 1) v = fmaf(p, T[best * C_ + cur], v);
        }
        #pragma unroll
        for (int o = 32; o >= 1; o >>= 1) v += __shfl_xor(v, o);
        if (l == 0) scores_p[n * KCH + k] = v;
        return;
    }

    // ---------------- wave 0: chunk matrix product (r6-verified) --------
    const int cc = l & 31;
    const int h  = l >> 5;

    const float* pm = pad + (size_t)n * S_;
    float ls = 0.f;
    for (int t = l; t < S_; t += 64) ls += pm[t];
    #pragma unroll
    for (int o = 32; o >= 1; o >>= 1) ls += __shfl_xor(ls, o);
    const int len = (int)(ls + 0.5f);

    float* Bout = Bg + ((size_t)n * KCH + k) * (C_ * C_);
    const int lo = k * LC;
    const int hi = min(lo + LC, len - 1);

    if (lo >= len - 1) {   // empty chunk -> identity
        #pragma unroll
        for (int qq = 0; qq < 16; ++qq) {
            const int row = (qq & 3) + 8 * (qq >> 2) + 4 * h;
            Bout[row * C_ + cc] = (row == cc) ? 1.f : 0.f;
        }
        if (l == 0) chunk_ls[n * KCH + k] = 0.f;
        return;
    }

    const int cnt = hi - lo;

    const float* npn = npots + ((size_t)n * S_ + lo) * C_;
    for (int qd = l * 4; qd < cnt * C_; qd += 256) {
        const float4 v = *(const float4*)(npn + qd);
        *(float4*)&e_lds[qd] = make_float4(expf(v.x), expf(v.y), expf(v.z), expf(v.w));
    }
    asm volatile("s_waitcnt lgkmcnt(0)" ::: "memory");

    float glo[8], ghi[8];
    {
        const float* el = e_lds + (size_t)(cnt - 1) * C_;
        #pragma unroll
        for (int j = 0; j < 8; ++j) {
            const int kk = 8 * h + j;
            glo[j] = el[kk]      * expf(T[kk * C_ + cc]);
            ghi[j] = el[kk + 16] * expf(T[(kk + 16) * C_ + cc]);
        }
    }

    if (cnt == 1) {
        #pragma unroll
        for (int j = 0; j < 8; ++j) {
            Bout[(8 * h + j) * C_ + cc]      = glo[j];
            Bout[(8 * h + j + 16) * C_ + cc] = ghi[j];
        }
        if (l == 0) chunk_ls[n * KCH + k] = 0.f;
        return;
    }

    union { unsigned u[4]; bf16x8 v; } ETalo, ETahi, blo, bhi;
    #pragma unroll
    for (int t = 0; t < 4; ++t) {
        const int kk = 8 * h + 2 * t;
        ETalo.u[t] = cvt_pk_bf16(expf(T[cc * C_ + kk]),      expf(T[cc * C_ + kk + 1]));
        ETahi.u[t] = cvt_pk_bf16(expf(T[cc * C_ + kk + 16]), expf(T[cc * C_ + kk + 17]));
        blo.u[t]   = cvt_pk_bf16(glo[2 * t], glo[2 * t + 1]);
        bhi.u[t]   = cvt_pk_bf16(ghi[2 * t], ghi[2 * t + 1]);
    }

    float logscale = 0.f;
    int it = 0;
    for (int i = hi - 2; i >= lo; --i) {
        f32x16 d = {};
        d = __builtin_amdgcn_mfma_f32_32x32x16_bf16(ETalo.v, blo.v, d, 0, 0, 0);
        d = __builtin_amdgcn_mfma_f32_32x32x16_bf16(ETahi.v, bhi.v, d, 0, 0, 0);

        const float* ep = e_lds + (i - lo) * C_ + 4 * h;
        const float4 e0 = *(const float4*)(ep);
        const float4 e1 = *(const float4*)(ep + 8);
        const float4 e2 = *(const float4*)(ep + 16);
        const float4 e3 = *(const float4*)(ep + 24);
        float sd[16];
        sd[0]  = d[0]  * e0.x;  sd[1]  = d[1]  * e0.y;  sd[2]  = d[2]  * e0.z;  sd[3]  = d[3]  * e0.w;
        sd[4]  = d[4]  * e1.x;  sd[5]  = d[5]  * e1.y;  sd[6]  = d[6]  * e1.z;  sd[7]  = d[7]  * e1.w;
        sd[8]  = d[8]  * e2.x;  sd[9]  = d[9]  * e2.y;  sd[10] = d[10] * e2.z;  sd[11] = d[11] * e2.w;
        sd[12] = d[12] * e3.x;  sd[13] = d[13] * e3.y;  sd[14] = d[14] * e3.z;  sd[15] = d[15] * e3.w;

        if ((++it & 7) == 0) {
            float m = sd[0];
            #pragma unroll
            for (int qq = 1; qq < 16; ++qq) m = fmaxf(m, sd[qq]);
            #pragma unroll
            for (int o = 32; o >= 1; o >>= 1) m = fmaxf(m, __shfl_xor(m, o));
            logscale += logf(m);
            const float inv = 1.f / m;
            #pragma unroll
            for (int qq = 0; qq < 16; ++qq) sd[qq] *= inv;
        }

        if (i > lo) {
            // D -> next B-operand. Halved exchange: send the word the partner
            // needs (verified against the r6 8-shfl mapping lane-by-lane):
            //   blo = h ? {x2,x3,w2,w3} : {w0,w1,x0,x1}
            //   bhi = h ? {x6,x7,w6,w7} : {w4,w5,x4,x5},  x_i = partner's w_i
            const unsigned w0 = cvt_pk_bf16(sd[0],  sd[1]);
            const unsigned w1 = cvt_pk_bf16(sd[2],  sd[3]);
            const unsigned w2 = cvt_pk_bf16(sd[4],  sd[5]);
            const unsigned w3 = cvt_pk_bf16(sd[6],  sd[7]);
            const unsigned w4 = cvt_pk_bf16(sd[8],  sd[9]);
            const unsigned w5 = cvt_pk_bf16(sd[10], sd[11]);
            const unsigned w6 = cvt_pk_bf16(sd[12], sd[13]);
            const unsigned w7 = cvt_pk_bf16(sd[14], sd[15]);
            const unsigned s0 = h ? w0 : w2;   // partner receives what it needs
            const unsigned s1 = h ? w1 : w3;
            const unsigned s2 = h ? w4 : w6;
            const unsigned s3 = h ? w5 : w7;
            const unsigned r0 = (unsigned)__shfl_xor((int)s0, 32);  // h0: x0 | h1: x2
            const unsigned r1 = (unsigned)__shfl_xor((int)s1, 32);  // h0: x1 | h1: x3
            const unsigned r2 = (unsigned)__shfl_xor((int)s2, 32);  // h0: x4 | h1: x6
            const unsigned r3 = (unsigned)__shfl_xor((int)s3, 32);  // h0: x5 | h1: x7
            blo.u[0] = h ? r0 : w0;
            blo.u[1] = h ? r1 : w1;
            blo.u[2] = h ? w2 : r0;
            blo.u[3] = h ? w3 : r1;
            bhi.u[0] = h ? r2 : w4;
            bhi.u[1] = h ? r3 : w5;
            bhi.u[2] = h ? w6 : r2;
            bhi.u[3] = h ? w7 : r3;
        } else {
            #pragma unroll
            for (int qq = 0; qq < 16; ++qq)
                Bout[((qq & 3) + 8 * (qq >> 2) + 4 * h) * C_ + cc] = sd[qq];
        }
    }
    if (l == 0) chunk_ls[n * KCH + k] = logscale;
}

// ---------------------------------------------------------------------------
// K3: combine + finalize. One wave per n. Combine loop = r11-verified (Bg from
// global); tail = r10/r11-verified atomic accumulate, 64th arrival writes out.
// ---------------------------------------------------------------------------
__global__ __launch_bounds__(64) void combine_tail(const float* __restrict__ npots,
                                                   const float* __restrict__ pad,
                                                   const float* __restrict__ Bg,
                                                   const float* __restrict__ chunk_ls,
                                                   const float* __restrict__ scores_p,
                                                   float* __restrict__ accum,
                                                   unsigned* __restrict__ cnt_all,
                                                   float* __restrict__ out) {
    const int n = blockIdx.x;
    const int l = threadIdx.x;
    const int r = l & 31;
    const int h = l >> 5;
    __shared__ __align__(16) float wcomb[32];

    const float* pm = pad + (size_t)n * S_;
    float ls = 0.f;
    for (int t = l; t < S_; t += 64) ls += pm[t];
    #pragma unroll
    for (int o = 32; o >= 1; o >>= 1) ls += __shfl_xor(ls, o);
    const int len = (int)(ls + 0.5f);

    float cls = (l < KCH) ? chunk_ls[n * KCH + l] : 0.f;
    #pragma unroll
    for (int o = 32; o >= 1; o >>= 1) cls += __shfl_xor(cls, o);

    float sc = (l < KCH) ? scores_p[n * KCH + l] : 0.f;
    #pragma unroll
    for (int o = 32; o >= 1; o >>= 1) sc += __shfl_xor(sc, o);

    const float np_last = npots[((size_t)n * S_ + (len - 1)) * C_ + r];
    float m0 = np_last;
    #pragma unroll
    for (int o = 32; o >= 1; o >>= 1) m0 = fmaxf(m0, __shfl_xor(m0, o));
    float logscale = m0 + cls;
    if (h == 0) wcomb[r] = expf(np_last - m0);
    asm volatile("s_waitcnt lgkmcnt(0)" ::: "memory");

    float sn = 0.f;
    for (int k2 = KCH - 1; k2 >= 0; --k2) {
        float cb[16], wv2[16];
        const float* Brow = Bg + ((size_t)n * KCH + k2) * (C_ * C_) + r * C_ + h * 16;
        #pragma unroll
        for (int t = 0; t < 4; ++t) *(float4*)&cb[t * 4] = *(const float4*)(Brow + t * 4);
        #pragma unroll
        for (int t = 0; t < 4; ++t) *(float4*)&wv2[t * 4] = *(const float4*)&wcomb[h * 16 + t * 4];
        float s = 0.f;
        #pragma unroll
        for (int t = 0; t < 16; ++t) s = fmaf(cb[t], wv2[t], s);
        s += __shfl_xor(s, 32);

        float m = s;
        #pragma unroll
        for (int o = 16; o >= 1; o >>= 1) m = fmaxf(m, __shfl_xor(m, o));
        logscale += logf(m);
        sn = s / m;
        if (h == 0) wcomb[r] = sn;
        asm volatile("s_waitcnt lgkmcnt(0)" ::: "memory");
    }
    float vz = (h == 0) ? sn : 0.f;
    #pragma unroll
    for (int o = 32; o >= 1; o >>= 1) vz += __shfl_xor(vz, o);
    const float logZn = logf(vz) + logscale;

    if (l == 0) {
        atomicAdd(accum, sc - logZn);                       // device-scope RMW
        asm volatile("s_waitcnt vmcnt(0)" ::: "memory");    // add performed
        const unsigned old = atomicAdd(cnt_all, 1u);
        if (old == (unsigned)(N_ - 1)) {
            const float total = atomicAdd(accum, 0.f);      // atomic read of final sum
            out[0] = -total / (float)N_;
        }
    }
}

// ---------------------------------------------------------------------------
extern "C" void kernel_launch(void* const* d_in, const int* in_sizes, int n_in,
                              void* d_out, int out_size, void* d_ws, size_t ws_size,
                              hipStream_t stream) {
    const float* X      = (const float*)d_in[0];
    const float* W      = (const float*)d_in[1];
    const float* T      = (const float*)d_in[2];
    const float* labels = (const float*)d_in[3];
    const float* pad    = (const float*)d_in[4];
    float* out = (float*)d_out;

    float*    npots    = (float*)d_ws;                       // 1,048,576 f
    float*    Bg       = npots + (size_t)N_ * S_ * C_;       // 1,048,576 f
    float*    chunk_ls = Bg + (size_t)N_ * KCH * C_ * C_;    // 1024 f
    float*    scores_p = chunk_ls + N_ * KCH;                // 1024 f
    float*    accum    = scores_p + N_ * KCH;                // 1 f
    unsigned* cnt_all  = (unsigned*)(accum + 1);             // 1 u32

    gemm_npots_mfma<<<(N_ * S_) / 128, 512, 0, stream>>>(X, W, npots, accum, cnt_all);
    chunk_score<<<dim3(N_, KCH), 128, 0, stream>>>(npots, pad, T, labels, Bg,
                                                   chunk_ls, scores_p);
    combine_tail<<<N_, 64, 0, stream>>>(npots, pad, Bg, chunk_ls, scores_p,
                                        accum, cnt_all, out);
}

// Round 13
// 54.700 us; speedup vs baseline: 2.4042x; 1.0007x over previous
//
#include <hip/hip_runtime.h>
#include <hip/hip_bf16.h>
#include <math.h>

#define N_ 64
#define S_ 512
#define D_ 768
#define C_ 32
#define KCH 16     // chunks per sequence (scan)
#define LC 32      // steps per chunk (scan)
#define WT_LD 772  // padded K stride for W^T in LDS

typedef __attribute__((ext_vector_type(8))) short bf16x8;
typedef __attribute__((ext_vector_type(4))) float f32x4;
typedef __attribute__((ext_vector_type(16))) float f32x16;

__device__ inline ushort f2bf(float x) {
    unsigned int b = __builtin_bit_cast(unsigned int, x);
    return (ushort)((b + 0x7FFFu + ((b >> 16) & 1u)) >> 16);   // RNE
}

__device__ inline unsigned cvt_pk_bf16(float lo, float hi) {   // D[15:0]=bf16(lo), D[31:16]=bf16(hi)
    unsigned r;
    asm("v_cvt_pk_bf16_f32 %0, %1, %2" : "=v"(r) : "v"(lo), "v"(hi));
    return r;
}

// ---------------------------------------------------------------------------
// K1: npots = X @ W via mfma_f32_16x16x32_bf16.
// FLAT FULL-K PREFETCH: each thread loads its entire X stream (48 x f32x4,
// 768 B) into registers up front -> ~48 loads in flight per thread (~48 KB/
// wave) instead of r12's 2-deep ping-pong (8 KB/wave). X is L3-resident in
// steady state; this hides the ~500-700 cy L3 latency at 2 waves/SIMD.
// W^T bf16 in LDS (r11/r12-verified). Block 0 zero-inits accum/cnt_all.
// VGPR ~225 (static-indexed register arrays); launch_bounds(512,2) caps at
// the 256-VGPR / 8-waves-per-CU point.
// ---------------------------------------------------------------------------
__global__ __launch_bounds__(512, 2) void gemm_npots_mfma(const float* __restrict__ X,
                                                          const float* __restrict__ W,
                                                          float* __restrict__ npots,
                                                          float* __restrict__ accum,
                                                          unsigned* __restrict__ cnt_all) {
    __shared__ ushort WtS[C_ * WT_LD];   // 49.4 KiB
    const int tid = threadIdx.x;

    if (blockIdx.x == 0 && tid == 0) { accum[0] = 0.f; cnt_all[0] = 0u; }

    for (int i = tid; i < D_ * C_; i += 512) {
        const int k = i >> 5, c = i & 31;
        WtS[c * WT_LD + k] = f2bf(W[i]);
    }
    __syncthreads();

    const int w  = tid >> 6;
    const int l  = tid & 63;
    const int lr = l & 15;
    const int q  = l >> 4;
    const int m0 = blockIdx.x * 128 + w * 16;

    const float*  xrow = X + (size_t)(m0 + lr) * D_ + q * 8;
    const ushort* wb0  = &WtS[lr * WT_LD + q * 8];
    const ushort* wb1  = wb0 + 16 * WT_LD;

    // ---- issue ALL X loads (static-indexed register arrays, no spill) ----
    f32x4 xa[24], xb[24];
    #pragma unroll
    for (int c = 0; c < 24; ++c) {
        xa[c] = *(const f32x4*)(xrow + c * 32);
        xb[c] = *(const f32x4*)(xrow + c * 32 + 4);
    }

    f32x4 acc0 = {0.f, 0.f, 0.f, 0.f};
    f32x4 acc1 = {0.f, 0.f, 0.f, 0.f};

    // ---- compute sweep; compiler inserts counted vmcnt per chunk ----
    #pragma unroll
    for (int c = 0; c < 24; ++c) {
        union { unsigned u[4]; bf16x8 v; } af;
        af.u[0] = cvt_pk_bf16(xa[c][0], xa[c][1]);
        af.u[1] = cvt_pk_bf16(xa[c][2], xa[c][3]);
        af.u[2] = cvt_pk_bf16(xb[c][0], xb[c][1]);
        af.u[3] = cvt_pk_bf16(xb[c][2], xb[c][3]);
        const bf16x8 b0 = *(const bf16x8*)(wb0 + c * 32);
        const bf16x8 b1 = *(const bf16x8*)(wb1 + c * 32);
        acc0 = __builtin_amdgcn_mfma_f32_16x16x32_bf16(af.v, b0, acc0, 0, 0, 0);
        acc1 = __builtin_amdgcn_mfma_f32_16x16x32_bf16(af.v, b1, acc1, 0, 0, 0);
    }

    const int r0 = m0 + q * 4;   // D: col=lane&15, row=(lane>>4)*4+reg
    #pragma unroll
    for (int reg = 0; reg < 4; ++reg) {
        npots[(size_t)(r0 + reg) * C_ + lr]      = acc0[reg];
        npots[(size_t)(r0 + reg) * C_ + lr + 16] = acc1[reg];
    }
}

// ---------------------------------------------------------------------------
// K2: block (n,k), 128 thr. Wave0: chunk product -> Bg. Wave1: score partial.
// (r12-verified, UNCHANGED)
// ---------------------------------------------------------------------------
__global__ __launch_bounds__(128) void chunk_score(const float* __restrict__ npots,
                                                   const float* __restrict__ pad,
                                                   const float* __restrict__ T,
                                                   const float* __restrict__ labels,
                                                   float* __restrict__ Bg,
                                                   float* __restrict__ chunk_ls,
                                                   float* __restrict__ scores_p) {
    const int n = blockIdx.x, k = blockIdx.y;
    const int tid = threadIdx.x;
    const int l = tid & 63;
    __shared__ __align__(16) float e_lds[LC * C_];

    if (tid >= 64) {
        const int tb = k * LC;
        int best = 0;
        if (l <= LC) {
            const int t = tb - 1 + l;
            if (t >= 0) {
                const float* lrow = labels + ((size_t)n * S_ + t) * C_;
                float bv = lrow[0];
                #pragma unroll
                for (int c = 1; c < C_; ++c) {
                    const float x = lrow[c];
                    if (x > bv) { bv = x; best = c; }
                }
            }
        }
        const int cur = __shfl(best, l + 1);
        float v = 0.f;
        if (l < LC) {
            const int t = tb + l;
            const float p = pad[(size_t)n * S_ + t];
            v = p * npots[((size_t)n * S_ + t) * C_ + cur];
            if (t >= 1) v = fmaf(p, T[best * C_ + cur], v);
        }
        #pragma unroll
        for (int o = 32; o >= 1; o >>= 1) v += __shfl_xor(v, o);
        if (l == 0) scores_p[n * KCH + k] = v;
        return;
    }

    const int cc = l & 31;
    const int h  = l >> 5;

    const float* pm = pad + (size_t)n * S_;
    float ls = 0.f;
    for (int t = l; t < S_; t += 64) ls += pm[t];
    #pragma unroll
    for (int o = 32; o >= 1; o >>= 1) ls += __shfl_xor(ls, o);
    const int len = (int)(ls + 0.5f);

    float* Bout = Bg + ((size_t)n * KCH + k) * (C_ * C_);
    const int lo = k * LC;
    const int hi = min(lo + LC, len - 1);

    if (lo >= len - 1) {   // empty chunk -> identity
        #pragma unroll
        for (int qq = 0; qq < 16; ++qq) {
            const int row = (qq & 3) + 8 * (qq >> 2) + 4 * h;
            Bout[row * C_ + cc] = (row == cc) ? 1.f : 0.f;
        }
        if (l == 0) chunk_ls[n * KCH + k] = 0.f;
        return;
    }

    const int cnt = hi - lo;

    const float* npn = npots + ((size_t)n * S_ + lo) * C_;
    for (int qd = l * 4; qd < cnt * C_; qd += 256) {
        const float4 v = *(const float4*)(npn + qd);
        *(float4*)&e_lds[qd] = make_float4(expf(v.x), expf(v.y), expf(v.z), expf(v.w));
    }
    asm volatile("s_waitcnt lgkmcnt(0)" ::: "memory");

    float glo[8], ghi[8];
    {
        const float* el = e_lds + (size_t)(cnt - 1) * C_;
        #pragma unroll
        for (int j = 0; j < 8; ++j) {
            const int kk = 8 * h + j;
            glo[j] = el[kk]      * expf(T[kk * C_ + cc]);
            ghi[j] = el[kk + 16] * expf(T[(kk + 16) * C_ + cc]);
        }
    }

    if (cnt == 1) {
        #pragma unroll
        for (int j = 0; j < 8; ++j) {
            Bout[(8 * h + j) * C_ + cc]      = glo[j];
            Bout[(8 * h + j + 16) * C_ + cc] = ghi[j];
        }
        if (l == 0) chunk_ls[n * KCH + k] = 0.f;
        return;
    }

    union { unsigned u[4]; bf16x8 v; } ETalo, ETahi, blo, bhi;
    #pragma unroll
    for (int t = 0; t < 4; ++t) {
        const int kk = 8 * h + 2 * t;
        ETalo.u[t] = cvt_pk_bf16(expf(T[cc * C_ + kk]),      expf(T[cc * C_ + kk + 1]));
        ETahi.u[t] = cvt_pk_bf16(expf(T[cc * C_ + kk + 16]), expf(T[cc * C_ + kk + 17]));
        blo.u[t]   = cvt_pk_bf16(glo[2 * t], glo[2 * t + 1]);
        bhi.u[t]   = cvt_pk_bf16(ghi[2 * t], ghi[2 * t + 1]);
    }

    float logscale = 0.f;
    int it = 0;
    for (int i = hi - 2; i >= lo; --i) {
        f32x16 d = {};
        d = __builtin_amdgcn_mfma_f32_32x32x16_bf16(ETalo.v, blo.v, d, 0, 0, 0);
        d = __builtin_amdgcn_mfma_f32_32x32x16_bf16(ETahi.v, bhi.v, d, 0, 0, 0);

        const float* ep = e_lds + (i - lo) * C_ + 4 * h;
        const float4 e0 = *(const float4*)(ep);
        const float4 e1 = *(const float4*)(ep + 8);
        const float4 e2 = *(const float4*)(ep + 16);
        const float4 e3 = *(const float4*)(ep + 24);
        float sd[16];
        sd[0]  = d[0]  * e0.x;  sd[1]  = d[1]  * e0.y;  sd[2]  = d[2]  * e0.z;  sd[3]  = d[3]  * e0.w;
        sd[4]  = d[4]  * e1.x;  sd[5]  = d[5]  * e1.y;  sd[6]  = d[6]  * e1.z;  sd[7]  = d[7]  * e1.w;
        sd[8]  = d[8]  * e2.x;  sd[9]  = d[9]  * e2.y;  sd[10] = d[10] * e2.z;  sd[11] = d[11] * e2.w;
        sd[12] = d[12] * e3.x;  sd[13] = d[13] * e3.y;  sd[14] = d[14] * e3.z;  sd[15] = d[15] * e3.w;

        if ((++it & 7) == 0) {
            float m = sd[0];
            #pragma unroll
            for (int qq = 1; qq < 16; ++qq) m = fmaxf(m, sd[qq]);
            #pragma unroll
            for (int o = 32; o >= 1; o >>= 1) m = fmaxf(m, __shfl_xor(m, o));
            logscale += logf(m);
            const float inv = 1.f / m;
            #pragma unroll
            for (int qq = 0; qq < 16; ++qq) sd[qq] *= inv;
        }

        if (i > lo) {
            const unsigned w0 = cvt_pk_bf16(sd[0],  sd[1]);
            const unsigned w1 = cvt_pk_bf16(sd[2],  sd[3]);
            const unsigned w2 = cvt_pk_bf16(sd[4],  sd[5]);
            const unsigned w3 = cvt_pk_bf16(sd[6],  sd[7]);
            const unsigned w4 = cvt_pk_bf16(sd[8],  sd[9]);
            const unsigned w5 = cvt_pk_bf16(sd[10], sd[11]);
            const unsigned w6 = cvt_pk_bf16(sd[12], sd[13]);
            const unsigned w7 = cvt_pk_bf16(sd[14], sd[15]);
            const unsigned s0 = h ? w0 : w2;
            const unsigned s1 = h ? w1 : w3;
            const unsigned s2 = h ? w4 : w6;
            const unsigned s3 = h ? w5 : w7;
            const unsigned r0 = (unsigned)__shfl_xor((int)s0, 32);
            const unsigned r1 = (unsigned)__shfl_xor((int)s1, 32);
            const unsigned r2 = (unsigned)__shfl_xor((int)s2, 32);
            const unsigned r3 = (unsigned)__shfl_xor((int)s3, 32);
            blo.u[0] = h ? r0 : w0;
            blo.u[1] = h ? r1 : w1;
            blo.u[2] = h ? w2 : r0;
            blo.u[3] = h ? w3 : r1;
            bhi.u[0] = h ? r2 : w4;
            bhi.u[1] = h ? r3 : w5;
            bhi.u[2] = h ? w6 : r2;
            bhi.u[3] = h ? w7 : r3;
        } else {
            #pragma unroll
            for (int qq = 0; qq < 16; ++qq)
                Bout[((qq & 3) + 8 * (qq >> 2) + 4 * h) * C_ + cc] = sd[qq];
        }
    }
    if (l == 0) chunk_ls[n * KCH + k] = logscale;
}

// ---------------------------------------------------------------------------
// K3: combine + finalize. One wave per n. (r12-verified, UNCHANGED)
// ---------------------------------------------------------------------------
__global__ __launch_bounds__(64) void combine_tail(const float* __restrict__ npots,
                                                   const float* __restrict__ pad,
                                                   const float* __restrict__ Bg,
                                                   const float* __restrict__ chunk_ls,
                                                   const float* __restrict__ scores_p,
                                                   float* __restrict__ accum,
                                                   unsigned* __restrict__ cnt_all,
                                                   float* __restrict__ out) {
    const int n = blockIdx.x;
    const int l = threadIdx.x;
    const int r = l & 31;
    const int h = l >> 5;
    __shared__ __align__(16) float wcomb[32];

    const float* pm = pad + (size_t)n * S_;
    float ls = 0.f;
    for (int t = l; t < S_; t += 64) ls += pm[t];
    #pragma unroll
    for (int o = 32; o >= 1; o >>= 1) ls += __shfl_xor(ls, o);
    const int len = (int)(ls + 0.5f);

    float cls = (l < KCH) ? chunk_ls[n * KCH + l] : 0.f;
    #pragma unroll
    for (int o = 32; o >= 1; o >>= 1) cls += __shfl_xor(cls, o);

    float sc = (l < KCH) ? scores_p[n * KCH + l] : 0.f;
    #pragma unroll
    for (int o = 32; o >= 1; o >>= 1) sc += __shfl_xor(sc, o);

    const float np_last = npots[((size_t)n * S_ + (len - 1)) * C_ + r];
    float m0 = np_last;
    #pragma unroll
    for (int o = 32; o >= 1; o >>= 1) m0 = fmaxf(m0, __shfl_xor(m0, o));
    float logscale = m0 + cls;
    if (h == 0) wcomb[r] = expf(np_last - m0);
    asm volatile("s_waitcnt lgkmcnt(0)" ::: "memory");

    float sn = 0.f;
    for (int k2 = KCH - 1; k2 >= 0; --k2) {
        float cb[16], wv2[16];
        const float* Brow = Bg + ((size_t)n * KCH + k2) * (C_ * C_) + r * C_ + h * 16;
        #pragma unroll
        for (int t = 0; t < 4; ++t) *(float4*)&cb[t * 4] = *(const float4*)(Brow + t * 4);
        #pragma unroll
        for (int t = 0; t < 4; ++t) *(float4*)&wv2[t * 4] = *(const float4*)&wcomb[h * 16 + t * 4];
        float s = 0.f;
        #pragma unroll
        for (int t = 0; t < 16; ++t) s = fmaf(cb[t], wv2[t], s);
        s += __shfl_xor(s, 32);

        float m = s;
        #pragma unroll
        for (int o = 16; o >= 1; o >>= 1) m = fmaxf(m, __shfl_xor(m, o));
        logscale += logf(m);
        sn = s / m;
        if (h == 0) wcomb[r] = sn;
        asm volatile("s_waitcnt lgkmcnt(0)" ::: "memory");
    }
    float vz = (h == 0) ? sn : 0.f;
    #pragma unroll
    for (int o = 32; o >= 1; o >>= 1) vz += __shfl_xor(vz, o);
    const float logZn = logf(vz) + logscale;

    if (l == 0) {
        atomicAdd(accum, sc - logZn);
        asm volatile("s_waitcnt vmcnt(0)" ::: "memory");
        const unsigned old = atomicAdd(cnt_all, 1u);
        if (old == (unsigned)(N_ - 1)) {
            const float total = atomicAdd(accum, 0.f);
            out[0] = -total / (float)N_;
        }
    }
}

// ---------------------------------------------------------------------------
extern "C" void kernel_launch(void* const* d_in, const int* in_sizes, int n_in,
                              void* d_out, int out_size, void* d_ws, size_t ws_size,
                              hipStream_t stream) {
    const float* X      = (const float*)d_in[0];
    const float* W      = (const float*)d_in[1];
    const float* T      = (const float*)d_in[2];
    const float* labels = (const float*)d_in[3];
    const float* pad    = (const float*)d_in[4];
    float* out = (float*)d_out;

    float*    npots    = (float*)d_ws;                       // 1,048,576 f
    float*    Bg       = npots + (size_t)N_ * S_ * C_;       // 1,048,576 f
    float*    chunk_ls = Bg + (size_t)N_ * KCH * C_ * C_;    // 1024 f
    float*    scores_p = chunk_ls + N_ * KCH;                // 1024 f
    float*    accum    = scores_p + N_ * KCH;                // 1 f
    unsigned* cnt_all  = (unsigned*)(accum + 1);             // 1 u32

    gemm_npots_mfma<<<(N_ * S_) / 128, 512, 0, stream>>>(X, W, npots, accum, cnt_all);
    chunk_score<<<dim3(N_, KCH), 128, 0, stream>>>(npots, pad, T, labels, Bg,
                                                   chunk_ls, scores_p);
    combine_tail<<<N_, 64, 0, stream>>>(npots, pad, Bg, chunk_ls, scores_p,
                                        accum, cnt_all, out);
}